// Round 6
// baseline (7954.462 us; speedup 1.0000x reference)
//
#include <hip/hip_runtime.h>
#include <math.h>

#define E 262144
#define Nn 16384
#define H 8
#define D 64
#define HD 512
#define HID 256

typedef float f32x4 __attribute__((ext_vector_type(4)));
typedef short bf16x8 __attribute__((ext_vector_type(8)));

__device__ __forceinline__ float wave_sum(float v) {
    #pragma unroll
    for (int m = 1; m < 64; m <<= 1) v += __shfl_xor(v, m, 64);
    return v;
}

__device__ __forceinline__ unsigned short f2bf(float f) {
    unsigned u = __float_as_uint(f);
    return (unsigned short)((u + 0x7fffu + ((u >> 16) & 1u)) >> 16);
}

__device__ __forceinline__ void gl_lds16(const void* g, void* l) {
    __builtin_amdgcn_global_load_lds(
        (const __attribute__((address_space(1))) void*)g,
        (__attribute__((address_space(3))) void*)l, 16, 0, 0);
}

// v[h][j] = sum_d atten[h][d] * Wq[d][j]
__global__ void prep_v(const float* __restrict__ atten, const float* __restrict__ Wq,
                       float* __restrict__ v) {
    int t = threadIdx.x;            // 512 threads
    int h = t >> 6, j = t & 63;
    float a = 0.f;
    #pragma unroll 8
    for (int d = 0; d < 64; ++d) a += atten[h * 64 + d] * Wq[d * 64 + j];
    v[h * 64 + j] = a;
}

// MLP weight images (bf16, MFMA-frag layout, kg-XOR bank swizzle baked in)
__global__ void prep_mlp(const float* __restrict__ fc1w, const float* __restrict__ fc2w,
                         unsigned short* __restrict__ B1img, unsigned short* __restrict__ B2img) {
    int i = blockIdx.x * 256 + threadIdx.x;   // 32768 total
    if (i < 16384) {
        int j = i & 7, g = i >> 3;
        int cs = g & 255, kgkt = g >> 8;
        int kg = kgkt & 3, kt = kgkt >> 2;
        int c = cs ^ kg;
        int k = kt * 32 + kg * 8 + j;
        B1img[i] = f2bf(fc1w[c * 64 + k]);
    } else {
        int i2 = i - 16384;
        int j = i2 & 7, g = i2 >> 3;
        int ds = g & 63, kgkt = g >> 6;
        int kg = kgkt & 3, kt = kgkt >> 2;
        int dd = ds ^ kg;
        int c = kt * 32 + kg * 8 + j;
        B2img[i2] = f2bf(fc2w[dd * 256 + c]);
    }
}

// GRU weights bf16 image for BN=32:
// wb[cb(16)][t(16)][m(6)][kg(4)][cs(32)][j(8)] = w[(m%3)*512 + cb*32 + (cs^kg)][t*32+kg*8+j]
__global__ void wprep(const float* __restrict__ w_ih, const float* __restrict__ w_hh,
                      unsigned short* __restrict__ wb) {
    int o = blockIdx.x * 256 + threadIdx.x;   // 1,572,864 total
    int slice = o / 6144;
    int w = o - slice * 6144;
    int t = slice & 15, cb = slice >> 4;
    int j = w & 7;
    int cs = (w >> 3) & 31;
    int kgm = w >> 8;
    int kg = kgm & 3, m = kgm >> 2;
    const float* wm = (m < 3) ? w_ih : w_hh;
    int row = (m % 3) * 512 + cb * 32 + (cs ^ kg);
    int k = t * 32 + kg * 8 + j;
    wb[o] = f2bf(wm[(size_t)row * 512 + k]);
}

// k[e][d] = 0.125 * sum_j x[e][j] * Wk[d][j]
__global__ __launch_bounds__(256) void compute_k(const float* __restrict__ x,
                                                 const float* __restrict__ Wk,
                                                 float* __restrict__ kbuf) {
    __shared__ float sWk[64][130];
    int t = threadIdx.x;
    for (int i = t; i < 64 * 128; i += 256) sWk[i >> 7][i & 127] = Wk[i];
    __syncthreads();
    int lane = t & 63, w = t >> 6;
    for (int e = blockIdx.x * 4 + w; e < E; e += gridDim.x * 4) {
        const float* xr = x + (size_t)e * 128;
        float acc = 0.f;
        #pragma unroll 8
        for (int j = 0; j < 128; ++j) acc += xr[j] * sWk[lane][j];
        kbuf[(size_t)e * 64 + lane] = acc * 0.125f;
    }
}

// slots = mu + exp(log_sigma) * norm_dist ; also emit bf16 h_g image
__global__ void init_slots(const float* __restrict__ nd, const float* __restrict__ mu,
                           const float* __restrict__ lsig, float* __restrict__ out,
                           unsigned short* __restrict__ h_g) {
    __shared__ float sMu[64], sSig[64];
    if (threadIdx.x < 64) {
        sMu[threadIdx.x]  = mu[threadIdx.x];
        sSig[threadIdx.x] = __expf(lsig[threadIdx.x]);
    }
    __syncthreads();
    size_t n4 = (size_t)E * HD / 4;
    size_t stride = (size_t)gridDim.x * blockDim.x;
    for (size_t i = (size_t)blockIdx.x * blockDim.x + threadIdx.x; i < n4; i += stride) {
        float4 v = ((const float4*)nd)[i];
        size_t flat = i * 4;
        int d0 = (int)(flat & 63);
        v.x = sMu[d0]     + sSig[d0]     * v.x;
        v.y = sMu[d0 + 1] + sSig[d0 + 1] * v.y;
        v.z = sMu[d0 + 2] + sSig[d0 + 2] * v.z;
        v.w = sMu[d0 + 3] + sSig[d0 + 3] * v.w;
        ((float4*)out)[i] = v;
        int e = (int)(flat >> 9);
        int k = (int)(flat & 511);
        int tt = k >> 5, kgg = (k >> 3) & 3, jo = k & 7;  // jo in {0,4}
        uint2 pk;
        pk.x = (unsigned)f2bf(v.x) | ((unsigned)f2bf(v.y) << 16);
        pk.y = (unsigned)f2bf(v.z) | ((unsigned)f2bf(v.w) << 16);
        *(uint2*)(h_g + ((size_t)(tt * 4 + kgg) * E + e) * 8 + jo) = pk;
    }
}

__global__ void seg_init(unsigned* __restrict__ segmax, float* __restrict__ segsum) {
    int i = blockIdx.x * 256 + threadIdx.x;
    if (i < Nn * H) { segmax[i] = 0u; segsum[i] = 0.f; }
}

// one wave per (e,h): LN(slots row) -> dot v_h -> leaky_relu -> alpha ; atomicMax into segmax
__global__ __launch_bounds__(256) void alpha_ln(const float* __restrict__ cur,
                                                const float* __restrict__ v,
                                                const float* __restrict__ lnw,
                                                const float* __restrict__ lnb,
                                                const int* __restrict__ eidx,
                                                float* __restrict__ alpha,
                                                unsigned* __restrict__ segmax) {
    int lane = threadIdx.x & 63, w = threadIdx.x >> 6;
    size_t p = (size_t)blockIdx.x * 4 + w;          // grid = E*H/4 exactly
    float x = cur[p * 64 + lane];
    float m = wave_sum(x) * (1.f / 64.f);
    float d = x - m;
    float var = wave_sum(d * d) * (1.f / 64.f);
    float rs = rsqrtf(var + 1e-5f);
    float ln = d * rs * lnw[lane] + lnb[lane];
    int h = (int)(p & 7);
    float dot = wave_sum(ln * v[h * 64 + lane]) * 0.125f;
    float a = dot >= 0.f ? dot : 0.2f * dot;
    if (lane == 0) {
        alpha[p] = a;
        int e = (int)(p >> 3);
        int id = eidx[e];
        unsigned b = __float_as_uint(a);
        unsigned enc = (b & 0x80000000u) ? ~b : (b | 0x80000000u);
        atomicMax(&segmax[id * 8 + h], enc);
    }
}

__global__ void exp_sum(const int* __restrict__ eidx, const unsigned* __restrict__ segmax,
                        float* __restrict__ alpha, float* __restrict__ segsum) {
    size_t p = (size_t)blockIdx.x * 256 + threadIdx.x;
    int e = (int)(p >> 3), h = (int)(p & 7);
    int id = eidx[e];
    unsigned u = segmax[id * 8 + h];
    float m = __uint_as_float((u & 0x80000000u) ? (u & 0x7fffffffu) : ~u);
    float val = __expf(alpha[p] - m);
    alpha[p] = val;
    atomicAdd(&segsum[id * 8 + h], val);
}

// normalize alpha + build u_g = bf16((k*alpha)) in [t][kg][E][8] layout. thread per edge.
__global__ __launch_bounds__(256) void prep_u(const float* __restrict__ kbuf,
                                              const float* __restrict__ alpha,
                                              const float* __restrict__ segsum,
                                              const int* __restrict__ eidx,
                                              unsigned short* __restrict__ u_g) {
    int e = blockIdx.x * 256 + threadIdx.x;
    int id = eidx[e];
    float a[8];
    #pragma unroll
    for (int h = 0; h < 8; ++h)
        a[h] = alpha[(size_t)e * 8 + h] / (segsum[id * 8 + h] + 1e-16f);
    float4 kv[16];
    const float4* kr = (const float4*)(kbuf + (size_t)e * 64);
    #pragma unroll
    for (int q = 0; q < 16; ++q) kv[q] = kr[q];
    const float* kf = (const float*)kv;
    #pragma unroll
    for (int tt = 0; tt < 16; ++tt) {
        float ah = a[tt >> 1];
        #pragma unroll
        for (int kg = 0; kg < 4; ++kg) {
            int dbase = (tt & 1) * 32 + kg * 8;
            bf16x8 v;
            #pragma unroll
            for (int j = 0; j < 8; ++j) v[j] = (short)f2bf(kf[dbase + j] * ah);
            *(bf16x8*)(u_g + ((size_t)(tt * 4 + kg) * E + e) * 8) = v;
        }
    }
}

// ---------------- MFMA GRU : BM=256 x BN=32, BK=32 ----------------
// A (u,h) wave-private: global -> frag VGPRs direct, 1-iter prefetch, named dbuf.
// W shared: LDS, triple-buffered, staged at top of iter (1-iter lead).
// One barrier per ts. Counted vmcnt(11) = 8 A-loads + 3 W gl_lds in flight.
__global__ __launch_bounds__(256, 2) void gru_mfma(
    const float* __restrict__ cur, const unsigned short* __restrict__ u_g,
    const unsigned short* __restrict__ h_g, const unsigned short* __restrict__ wb,
    const float* __restrict__ b_ih, const float* __restrict__ b_hh,
    float* __restrict__ nxt) {

    __shared__ unsigned short Wl[3][6144];   // 3 x 12 KB

    int bid = blockIdx.x;
    int lbid = (bid & 7) * 2048 + (bid >> 3);   // XCD-contiguous chunks (16384 % 8 == 0)
    int eb = lbid >> 4, cb = lbid & 15;
    int e0 = eb * 256;
    int t = threadIdx.x;
    int lane = t & 63, wid = t >> 6;
    int li = lane & 15, kg = lane >> 4;
    int EB = wid * 64;

    const unsigned short* wsl = wb + (size_t)(cb * 16) * 6144;
    // per-lane A offset for ts=0, m: ((kg)*E + e0+EB+m*16+li)*8
    size_t abase = ((size_t)kg * E + (size_t)(e0 + EB + li)) * 8;

    f32x4 acc[4][4][2] = {};   // [plane][m][f]

    auto load_a = [&](int ts, bf16x8 (&au)[4], bf16x8 (&ah)[4]) {
        size_t o = abase + (size_t)ts * 4 * E * 8;
        #pragma unroll
        for (int m = 0; m < 4; ++m) {
            au[m] = *(const bf16x8*)(u_g + o + (size_t)m * 128);
            ah[m] = *(const bf16x8*)(h_g + o + (size_t)m * 128);
        }
    };
    auto stage_w = [&](int ts, int s) {
        #pragma unroll
        for (int c = 0; c < 3; ++c) {
            int i = c * 256 + t;
            gl_lds16(wsl + ((size_t)ts * 768 + i) * 8,
                     &Wl[s][(size_t)(c * 256 + (t & ~63)) * 8]);
        }
    };
    auto compute = [&](int s, bf16x8 (&au)[4], bf16x8 (&ah)[4]) {
        const unsigned short* W = &Wl[s][0];
        #pragma unroll
        for (int f = 0; f < 2; ++f) {
            int cs = (f * 16 + li) ^ kg;
            bf16x8 bir = *(const bf16x8*)(W + ((size_t)(0 * 4 + kg) * 32 + cs) * 8);
            bf16x8 biz = *(const bf16x8*)(W + ((size_t)(1 * 4 + kg) * 32 + cs) * 8);
            bf16x8 bin = *(const bf16x8*)(W + ((size_t)(2 * 4 + kg) * 32 + cs) * 8);
            bf16x8 bhr = *(const bf16x8*)(W + ((size_t)(3 * 4 + kg) * 32 + cs) * 8);
            bf16x8 bhz = *(const bf16x8*)(W + ((size_t)(4 * 4 + kg) * 32 + cs) * 8);
            bf16x8 bhn = *(const bf16x8*)(W + ((size_t)(5 * 4 + kg) * 32 + cs) * 8);
            #pragma unroll
            for (int m = 0; m < 4; ++m) {
                acc[0][m][f] = __builtin_amdgcn_mfma_f32_16x16x32_bf16(au[m], bir, acc[0][m][f], 0, 0, 0);
                acc[1][m][f] = __builtin_amdgcn_mfma_f32_16x16x32_bf16(au[m], biz, acc[1][m][f], 0, 0, 0);
                acc[2][m][f] = __builtin_amdgcn_mfma_f32_16x16x32_bf16(au[m], bin, acc[2][m][f], 0, 0, 0);
                acc[0][m][f] = __builtin_amdgcn_mfma_f32_16x16x32_bf16(ah[m], bhr, acc[0][m][f], 0, 0, 0);
                acc[1][m][f] = __builtin_amdgcn_mfma_f32_16x16x32_bf16(ah[m], bhz, acc[1][m][f], 0, 0, 0);
                acc[3][m][f] = __builtin_amdgcn_mfma_f32_16x16x32_bf16(ah[m], bhn, acc[3][m][f], 0, 0, 0);
            }
        }
    };

    bf16x8 auA[4], ahA[4], auB[4], ahB[4];

    // prologue: ts=0 operands in flight (11 vmem ops)
    load_a(0, auA, ahA);
    stage_w(0, 0);

    #pragma unroll 1
    for (int ts = 0; ts < 16; ts += 2) {
        {   // even: compute ts with A-bufA, W slab ts%3; prefetch ts+1 -> B
            int tn = (ts + 1 < 16) ? ts + 1 : 15;
            load_a(tn, auB, ahB);
            stage_w(tn, (ts + 1) % 3);
            asm volatile("s_waitcnt vmcnt(11)" ::: "memory");
            __builtin_amdgcn_s_barrier();
            compute(ts % 3, auA, ahA);
        }
        {   // odd: compute ts+1 with A-bufB; prefetch ts+2 -> A
            int tn = (ts + 2 < 16) ? ts + 2 : 15;
            load_a(tn, auA, ahA);
            stage_w(tn, (ts + 2) % 3);
            asm volatile("s_waitcnt vmcnt(11)" ::: "memory");
            __builtin_amdgcn_s_barrier();
            compute((ts + 1) % 3, auB, ahB);
        }
    }

    // epilogue: gates f32
    #pragma unroll
    for (int f = 0; f < 2; ++f) {
        int c = cb * 32 + f * 16 + li;
        float br = b_ih[c] + b_hh[c];
        float bz = b_ih[c + 512] + b_hh[c + 512];
        float bi = b_ih[c + 1024];
        float bh = b_hh[c + 1024];
        #pragma unroll
        for (int m = 0; m < 4; ++m) {
            #pragma unroll
            for (int q = 0; q < 4; ++q) {
                size_t ge = (size_t)(e0 + EB + m * 16 + kg * 4 + q);
                float r = 1.f / (1.f + __expf(-(acc[0][m][f][q] + br)));
                float z = 1.f / (1.f + __expf(-(acc[1][m][f][q] + bz)));
                float n = tanhf(acc[2][m][f][q] + bi + r * (acc[3][m][f][q] + bh));
                float hp = cur[ge * 512 + c];
                nxt[ge * 512 + c] = (1.f - z) * n + z * hp;
            }
        }
    }
}

// ---------------- MFMA MLP (fused LN + fc1 + relu + fc2 + residual + h_g emit) ----------------
__global__ __launch_bounds__(256, 2) void mlp_mfma(
    float* __restrict__ slots,
    const unsigned short* __restrict__ B1img, const unsigned short* __restrict__ B2img,
    const float* __restrict__ lnw, const float* __restrict__ lnb,
    const float* __restrict__ fc1b, const float* __restrict__ fc2b,
    unsigned short* __restrict__ h_g, int write_hg) {

    __shared__ unsigned short A1[4096];    // frag tile, later reused as [row64][d64] bf16
    __shared__ unsigned short Bst[8192];   // weight staging chunk 16 KB
    __shared__ unsigned short Y1[16384];   // 32 KB

    int t = threadIdx.x;
    int lane = t & 63, wid = t >> 6;
    int li = lane & 15, kg = lane >> 4;
    size_t p0 = (size_t)blockIdx.x * 64;

    // ---- phase 0: load rows, LN (4 threads/row), bf16 A1 tile ----
    {
        int r = t >> 2, c0 = (t & 3) * 16;
        const float* rowp = slots + (p0 + r) * 64 + c0;
        float4 x0 = ((const float4*)rowp)[0];
        float4 x1 = ((const float4*)rowp)[1];
        float4 x2 = ((const float4*)rowp)[2];
        float4 x3 = ((const float4*)rowp)[3];
        float s = x0.x + x0.y + x0.z + x0.w + x1.x + x1.y + x1.z + x1.w
                + x2.x + x2.y + x2.z + x2.w + x3.x + x3.y + x3.z + x3.w;
        s += __shfl_xor(s, 1, 64); s += __shfl_xor(s, 2, 64);
        float m = s * (1.f / 64.f);
        float xv[16] = {x0.x, x0.y, x0.z, x0.w, x1.x, x1.y, x1.z, x1.w,
                        x2.x, x2.y, x2.z, x2.w, x3.x, x3.y, x3.z, x3.w};
        float sq = 0.f;
        #pragma unroll
        for (int i = 0; i < 16; ++i) { float dd = xv[i] - m; sq += dd * dd; }
        sq += __shfl_xor(sq, 1, 64); sq += __shfl_xor(sq, 2, 64);
        float rs = rsqrtf(sq * (1.f / 64.f) + 1e-5f);
        unsigned short u[16];
        #pragma unroll
        for (int i = 0; i < 16; ++i)
            u[i] = f2bf((xv[i] - m) * rs * lnw[c0 + i] + lnb[c0 + i]);
        int g0 = (t & 3) * 2, g1 = g0 + 1;
        *(bf16x8*)(A1 + g0 * 512 + ((r * 8) ^ ((g0 & 3) * 8))) = *(bf16x8*)&u[0];
        *(bf16x8*)(A1 + g1 * 512 + ((r * 8) ^ ((g1 & 3) * 8))) = *(bf16x8*)&u[8];
    }
    __syncthreads();

    // ---- fc1 (swapped): acc1[ct][rt] ----
    f32x4 acc1[4][4] = {};
    #pragma unroll
    for (int kt = 0; kt < 2; ++kt) {
        {   // stage 16KB chunk of B1img via global_load_lds
            #pragma unroll
            for (int c = 0; c < 4; ++c) {
                int i = c * 256 + t;
                gl_lds16(B1img + (size_t)kt * 8192 + (size_t)i * 8,
                         Bst + (size_t)(c * 256 + (t & ~63)) * 8);
            }
        }
        __syncthreads();
        bf16x8 bfrag[4];
        #pragma unroll
        for (int rt = 0; rt < 4; ++rt)
            bfrag[rt] = *(bf16x8*)(A1 + (kt * 4 + kg) * 512 + (((rt * 16 + li) * 8) ^ (kg * 8)));
        #pragma unroll
        for (int ct = 0; ct < 4; ++ct) {
            bf16x8 af = *(bf16x8*)(Bst + kg * 2048 + (((wid * 64 + ct * 16 + li) ^ kg) * 8));
            #pragma unroll
            for (int rt = 0; rt < 4; ++rt)
                acc1[ct][rt] = __builtin_amdgcn_mfma_f32_16x16x32_bf16(af, bfrag[rt], acc1[ct][rt], 0, 0, 0);
        }
        __syncthreads();
    }

    // ---- bias + relu + bf16, packed b64 writes into Y1 ----
    #pragma unroll
    for (int ct = 0; ct < 4; ++ct) {
        int c0 = wid * 64 + ct * 16 + kg * 4;
        float4 b1 = *(const float4*)(fc1b + c0);
        int g = c0 >> 3;
        #pragma unroll
        for (int rt = 0; rt < 4; ++rt) {
            f32x4 vv = acc1[ct][rt];
            float y0 = fmaxf(vv[0] + b1.x, 0.f), y1v = fmaxf(vv[1] + b1.y, 0.f);
            float y2 = fmaxf(vv[2] + b1.z, 0.f), y3 = fmaxf(vv[3] + b1.w, 0.f);
            unsigned lo = (unsigned)f2bf(y0) | ((unsigned)f2bf(y1v) << 16);
            unsigned hi = (unsigned)f2bf(y2) | ((unsigned)f2bf(y3) << 16);
            int r = rt * 16 + li;
            int off = g * 512 + ((r * 8) ^ ((g & 3) * 8)) + (c0 & 7);
            uint2 pk; pk.x = lo; pk.y = hi;
            *(uint2*)(Y1 + off) = pk;
        }
    }
    __syncthreads();

    // ---- fc2 ----
    f32x4 acc2[4] = {};
    #pragma unroll
    for (int hc = 0; hc < 2; ++hc) {
        {   // stage 16KB chunk of B2img via global_load_lds
            #pragma unroll
            for (int c = 0; c < 4; ++c) {
                int i = c * 256 + t;
                gl_lds16(B2img + (size_t)hc * 8192 + (size_t)i * 8,
                         Bst + (size_t)(c * 256 + (t & ~63)) * 8);
            }
        }
        __syncthreads();
        #pragma unroll
        for (int ktl = 0; ktl < 4; ++ktl) {
            int ktg = hc * 4 + ktl;
            bf16x8 af = *(bf16x8*)(Y1 + (ktg * 4 + kg) * 512 + (((wid * 16 + li) * 8) ^ (kg * 8)));
            #pragma unroll
            for (int nt = 0; nt < 4; ++nt) {
                bf16x8 bf = *(bf16x8*)(Bst + (ktl * 4 + kg) * 512 + (((nt * 16 + li) ^ kg) * 8));
                acc2[nt] = __builtin_amdgcn_mfma_f32_16x16x32_bf16(af, bf, acc2[nt], 0, 0, 0);
            }
        }
        __syncthreads();
    }

    // ---- epilogue: residual add in-place; stash bf16 into A1 ----
    #pragma unroll
    for (int nt = 0; nt < 4; ++nt) {
        int dd = nt * 16 + li;
        float b2 = fc2b[dd];
        #pragma unroll
        for (int q = 0; q < 4; ++q) {
            int r = wid * 16 + kg * 4 + q;
            size_t gp = (p0 + r) * 64 + dd;
            float val = slots[gp] + acc2[nt][q] + b2;
            slots[gp] = val;
            A1[r * 64 + dd] = f2bf(val);
        }
    }
    if (write_hg) {
        __syncthreads();
        #pragma unroll
        for (int c2 = 0; c2 < 2; ++c2) {
            int n = c2 * 256 + t;           // 0..511 = (h*8+g)*8 + eloc
            int eloc = n & 7;
            int hg8 = n >> 3;
            int hh = hg8 >> 3, g = hg8 & 7;
            int r = eloc * 8 + hh;
            bf16x8 v = *(bf16x8*)(A1 + r * 64 + g * 8);
            int k = hh * 64 + g * 8;
            int tt = k >> 5, kgg = (k >> 3) & 3;
            size_t e = (size_t)blockIdx.x * 8 + eloc;
            *(bf16x8*)(h_g + ((size_t)(tt * 4 + kgg) * E + e) * 8) = v;
        }
    }
}

extern "C" void kernel_launch(void* const* d_in, const int* in_sizes, int n_in,
                              void* d_out, int out_size, void* d_ws, size_t ws_size,
                              hipStream_t stream) {
    const float* x     = (const float*)d_in[0];
    const int*   eidx  = (const int*)d_in[1];
    const float* nd    = (const float*)d_in[3];
    const float* mu    = (const float*)d_in[4];
    const float* lsig  = (const float*)d_in[5];
    const float* atten = (const float*)d_in[6];
    const float* ln_sw = (const float*)d_in[7];
    const float* ln_sb = (const float*)d_in[8];
    const float* ln_mw = (const float*)d_in[9];
    const float* ln_mb = (const float*)d_in[10];
    const float* Wq    = (const float*)d_in[11];
    const float* Wk    = (const float*)d_in[12];
    const float* w_ih  = (const float*)d_in[13];
    const float* w_hh  = (const float*)d_in[14];
    const float* b_ih  = (const float*)d_in[15];
    const float* b_hh  = (const float*)d_in[16];
    const float* fc1w  = (const float*)d_in[17];
    const float* fc1b  = (const float*)d_in[18];
    const float* fc2w  = (const float*)d_in[19];
    const float* fc2b  = (const float*)d_in[20];

    float* out = (float*)d_out;
    char* ws = (char*)d_ws;
    size_t off = 0;
    auto alloc = [&](size_t nbytes) {
        void* p = ws + off;
        off += (nbytes + 255) & ~(size_t)255;
        return p;
    };
    float*          slotsA = (float*)alloc((size_t)E * HD * 4);
    float*          kbuf   = (float*)alloc((size_t)E * 64 * 4);
    float*          alpha  = (float*)alloc((size_t)E * 8 * 4);
    unsigned*       segmax = (unsigned*)alloc((size_t)Nn * 8 * 4);
    float*          segsum = (float*)alloc((size_t)Nn * 8 * 4);
    float*          vbuf   = (float*)alloc(512 * 4);
    unsigned short* B1img  = (unsigned short*)alloc(16384 * 2);
    unsigned short* B2img  = (unsigned short*)alloc(16384 * 2);
    unsigned short* wb     = (unsigned short*)alloc((size_t)1572864 * 2);
    unsigned short* u_g    = (unsigned short*)alloc((size_t)E * HD * 2);
    unsigned short* h_g    = (unsigned short*)alloc((size_t)E * HD * 2);

    prep_v<<<1, 512, 0, stream>>>(atten, Wq, vbuf);
    prep_mlp<<<128, 256, 0, stream>>>(fc1w, fc2w, B1img, B2img);
    wprep<<<6144, 256, 0, stream>>>(w_ih, w_hh, wb);
    compute_k<<<4096, 256, 0, stream>>>(x, Wk, kbuf);
    init_slots<<<2048, 256, 0, stream>>>(nd, mu, lsig, slotsA, h_g);

    float* cur = slotsA;
    float* nxt = out;
    for (int it = 0; it < 3; ++it) {
        seg_init<<<512, 256, 0, stream>>>(segmax, segsum);
        alpha_ln<<<E * 8 / 4, 256, 0, stream>>>(cur, vbuf, ln_sw, ln_sb, eidx, alpha, segmax);
        exp_sum<<<E * 8 / 256, 256, 0, stream>>>(eidx, segmax, alpha, segsum);
        prep_u<<<E / 256, 256, 0, stream>>>(kbuf, alpha, segsum, eidx, u_g);
        gru_mfma<<<16384, 256, 0, stream>>>(cur, u_g, h_g, wb, b_ih, b_hh, nxt);
        mlp_mfma<<<32768, 256, 0, stream>>>(nxt, B1img, B2img, ln_mw, ln_mb, fc1b, fc2b,
                                            h_g, (it < 2) ? 1 : 0);
        float* tmp = cur; cur = nxt; nxt = tmp;
    }
    (void)in_sizes; (void)n_in; (void)out_size; (void)ws_size;
}

// Round 7
// 7271.743 us; speedup vs baseline: 1.0939x; 1.0939x over previous
//
#include <hip/hip_runtime.h>
#include <math.h>

#define E 262144
#define Nn 16384
#define H 8
#define D 64
#define HD 512
#define HID 256

typedef float f32x4 __attribute__((ext_vector_type(4)));
typedef short bf16x8 __attribute__((ext_vector_type(8)));

__device__ __forceinline__ float wave_sum(float v) {
    #pragma unroll
    for (int m = 1; m < 64; m <<= 1) v += __shfl_xor(v, m, 64);
    return v;
}

__device__ __forceinline__ unsigned short f2bf(float f) {
    unsigned u = __float_as_uint(f);
    return (unsigned short)((u + 0x7fffu + ((u >> 16) & 1u)) >> 16);
}

__device__ __forceinline__ void gl_lds16(const void* g, void* l) {
    __builtin_amdgcn_global_load_lds(
        (const __attribute__((address_space(1))) void*)g,
        (__attribute__((address_space(3))) void*)l, 16, 0, 0);
}

// v[h][j] = sum_d atten[h][d] * Wq[d][j]
__global__ void prep_v(const float* __restrict__ atten, const float* __restrict__ Wq,
                       float* __restrict__ v) {
    int t = threadIdx.x;            // 512 threads
    int h = t >> 6, j = t & 63;
    float a = 0.f;
    #pragma unroll 8
    for (int d = 0; d < 64; ++d) a += atten[h * 64 + d] * Wq[d * 64 + j];
    v[h * 64 + j] = a;
}

// MLP weight images (bf16, MFMA-frag layout, kg-XOR bank swizzle baked in)
__global__ void prep_mlp(const float* __restrict__ fc1w, const float* __restrict__ fc2w,
                         unsigned short* __restrict__ B1img, unsigned short* __restrict__ B2img) {
    int i = blockIdx.x * 256 + threadIdx.x;   // 32768 total
    if (i < 16384) {
        int j = i & 7, g = i >> 3;
        int cs = g & 255, kgkt = g >> 8;
        int kg = kgkt & 3, kt = kgkt >> 2;
        int c = cs ^ kg;
        int k = kt * 32 + kg * 8 + j;
        B1img[i] = f2bf(fc1w[c * 64 + k]);
    } else {
        int i2 = i - 16384;
        int j = i2 & 7, g = i2 >> 3;
        int ds = g & 63, kgkt = g >> 6;
        int kg = kgkt & 3, kt = kgkt >> 2;
        int dd = ds ^ kg;
        int c = kt * 32 + kg * 8 + j;
        B2img[i2] = f2bf(fc2w[dd * 256 + c]);
    }
}

// GRU weights bf16 image for BN=32:
// wb[cb(16)][t(16)][m(6)][kg(4)][cs(32)][j(8)] = w[(m%3)*512 + cb*32 + (cs^kg)][t*32+kg*8+j]
__global__ void wprep(const float* __restrict__ w_ih, const float* __restrict__ w_hh,
                      unsigned short* __restrict__ wb) {
    int o = blockIdx.x * 256 + threadIdx.x;   // 1,572,864 total
    int slice = o / 6144;
    int w = o - slice * 6144;
    int t = slice & 15, cb = slice >> 4;
    int j = w & 7;
    int cs = (w >> 3) & 31;
    int kgm = w >> 8;
    int kg = kgm & 3, m = kgm >> 2;
    const float* wm = (m < 3) ? w_ih : w_hh;
    int row = (m % 3) * 512 + cb * 32 + (cs ^ kg);
    int k = t * 32 + kg * 8 + j;
    wb[o] = f2bf(wm[(size_t)row * 512 + k]);
}

// k[e][d] = 0.125 * sum_j x[e][j] * Wk[d][j]
__global__ __launch_bounds__(256) void compute_k(const float* __restrict__ x,
                                                 const float* __restrict__ Wk,
                                                 float* __restrict__ kbuf) {
    __shared__ float sWk[64][130];
    int t = threadIdx.x;
    for (int i = t; i < 64 * 128; i += 256) sWk[i >> 7][i & 127] = Wk[i];
    __syncthreads();
    int lane = t & 63, w = t >> 6;
    for (int e = blockIdx.x * 4 + w; e < E; e += gridDim.x * 4) {
        const float* xr = x + (size_t)e * 128;
        float acc = 0.f;
        #pragma unroll 8
        for (int j = 0; j < 128; ++j) acc += xr[j] * sWk[lane][j];
        kbuf[(size_t)e * 64 + lane] = acc * 0.125f;
    }
}

// slots = mu + exp(log_sigma) * norm_dist ; also emit bf16 h_g image
__global__ void init_slots(const float* __restrict__ nd, const float* __restrict__ mu,
                           const float* __restrict__ lsig, float* __restrict__ out,
                           unsigned short* __restrict__ h_g) {
    __shared__ float sMu[64], sSig[64];
    if (threadIdx.x < 64) {
        sMu[threadIdx.x]  = mu[threadIdx.x];
        sSig[threadIdx.x] = __expf(lsig[threadIdx.x]);
    }
    __syncthreads();
    size_t n4 = (size_t)E * HD / 4;
    size_t stride = (size_t)gridDim.x * blockDim.x;
    for (size_t i = (size_t)blockIdx.x * blockDim.x + threadIdx.x; i < n4; i += stride) {
        float4 v = ((const float4*)nd)[i];
        size_t flat = i * 4;
        int d0 = (int)(flat & 63);
        v.x = sMu[d0]     + sSig[d0]     * v.x;
        v.y = sMu[d0 + 1] + sSig[d0 + 1] * v.y;
        v.z = sMu[d0 + 2] + sSig[d0 + 2] * v.z;
        v.w = sMu[d0 + 3] + sSig[d0 + 3] * v.w;
        ((float4*)out)[i] = v;
        int e = (int)(flat >> 9);
        int k = (int)(flat & 511);
        int tt = k >> 5, kgg = (k >> 3) & 3, jo = k & 7;  // jo in {0,4}
        uint2 pk;
        pk.x = (unsigned)f2bf(v.x) | ((unsigned)f2bf(v.y) << 16);
        pk.y = (unsigned)f2bf(v.z) | ((unsigned)f2bf(v.w) << 16);
        *(uint2*)(h_g + ((size_t)(tt * 4 + kgg) * E + e) * 8 + jo) = pk;
    }
}

__global__ void seg_init(unsigned* __restrict__ segmax, float* __restrict__ segsum) {
    int i = blockIdx.x * 256 + threadIdx.x;
    if (i < Nn * H) { segmax[i] = 0u; segsum[i] = 0.f; }
}

// one wave per (e,h): LN(slots row) -> dot v_h -> leaky_relu -> alpha ; atomicMax into segmax
// (used once, for iteration 0; later iterations fuse this into mlp_mfma's epilogue)
__global__ __launch_bounds__(256) void alpha_ln(const float* __restrict__ cur,
                                                const float* __restrict__ v,
                                                const float* __restrict__ lnw,
                                                const float* __restrict__ lnb,
                                                const int* __restrict__ eidx,
                                                float* __restrict__ alpha,
                                                unsigned* __restrict__ segmax) {
    int lane = threadIdx.x & 63, w = threadIdx.x >> 6;
    size_t p = (size_t)blockIdx.x * 4 + w;          // grid = E*H/4 exactly
    float x = cur[p * 64 + lane];
    float m = wave_sum(x) * (1.f / 64.f);
    float d = x - m;
    float var = wave_sum(d * d) * (1.f / 64.f);
    float rs = rsqrtf(var + 1e-5f);
    float ln = d * rs * lnw[lane] + lnb[lane];
    int h = (int)(p & 7);
    float dot = wave_sum(ln * v[h * 64 + lane]) * 0.125f;
    float a = dot >= 0.f ? dot : 0.2f * dot;
    if (lane == 0) {
        alpha[p] = a;
        int e = (int)(p >> 3);
        int id = eidx[e];
        unsigned b = __float_as_uint(a);
        unsigned enc = (b & 0x80000000u) ? ~b : (b | 0x80000000u);
        atomicMax(&segmax[id * 8 + h], enc);
    }
}

__global__ void exp_sum(const int* __restrict__ eidx, const unsigned* __restrict__ segmax,
                        float* __restrict__ alpha, float* __restrict__ segsum) {
    size_t p = (size_t)blockIdx.x * 256 + threadIdx.x;
    int e = (int)(p >> 3), h = (int)(p & 7);
    int id = eidx[e];
    unsigned u = segmax[id * 8 + h];
    float m = __uint_as_float((u & 0x80000000u) ? (u & 0x7fffffffu) : ~u);
    float val = __expf(alpha[p] - m);
    alpha[p] = val;
    atomicAdd(&segsum[id * 8 + h], val);
}

// normalize alpha + build u_g = bf16((k*alpha)) in [t][kg][E][8] layout. thread per edge.
__global__ __launch_bounds__(256) void prep_u(const float* __restrict__ kbuf,
                                              const float* __restrict__ alpha,
                                              const float* __restrict__ segsum,
                                              const int* __restrict__ eidx,
                                              unsigned short* __restrict__ u_g) {
    int e = blockIdx.x * 256 + threadIdx.x;
    int id = eidx[e];
    float a[8];
    #pragma unroll
    for (int h = 0; h < 8; ++h)
        a[h] = alpha[(size_t)e * 8 + h] / (segsum[id * 8 + h] + 1e-16f);
    float4 kv[16];
    const float4* kr = (const float4*)(kbuf + (size_t)e * 64);
    #pragma unroll
    for (int q = 0; q < 16; ++q) kv[q] = kr[q];
    const float* kf = (const float*)kv;
    #pragma unroll
    for (int tt = 0; tt < 16; ++tt) {
        float ah = a[tt >> 1];
        #pragma unroll
        for (int kg = 0; kg < 4; ++kg) {
            int dbase = (tt & 1) * 32 + kg * 8;
            bf16x8 v;
            #pragma unroll
            for (int j = 0; j < 8; ++j) v[j] = (short)f2bf(kf[dbase + j] * ah);
            *(bf16x8*)(u_g + ((size_t)(tt * 4 + kg) * E + e) * 8) = v;
        }
    }
}

// ---------------- MFMA GRU : BM=256 x BN=32, BK=32, dbuf-A + counted vmcnt ----------------
// LDS entries (16B each): bufA[p] at p*2048 (u [0,1024) = [kg][el], h [1024,2048));
// W at 4096 + [0,768). Total 4864 entries = 76 KB (dynamic LDS).
// Block->work map: cb partitioned BY XCD (2 slices per XCD, eb-paired) so the
// per-XCD L2 hot set is 2x192KB of weights + the paired edge strip (no thrash).
__global__ __launch_bounds__(256, 2) void gru_mfma(
    const float* __restrict__ cur, const unsigned short* __restrict__ u_g,
    const unsigned short* __restrict__ h_g, const unsigned short* __restrict__ wb,
    const float* __restrict__ b_ih, const float* __restrict__ b_hh,
    float* __restrict__ nxt) {

    extern __shared__ unsigned short lds[];

    int bid = blockIdx.x;
    int xcd = bid & 7, ii = bid >> 3;           // hardware round-robin: xcd = bid%8
    int eb = ii >> 1, cb = 2 * xcd + (ii & 1);  // cb fixed per XCD-pair; strips pair-reused
    int e0 = eb * 256;
    int t = threadIdx.x;
    int lane = t & 63, wid = t >> 6;
    int li = lane & 15, kg = lane >> 4;
    int EB = wid * 64;

    const unsigned short* wsl = wb + (size_t)(cb * 16) * 6144;

    f32x4 acc[4][4][2] = {};   // [plane][m][f]

    auto stage_a = [&](int ts, int p) {
        #pragma unroll
        for (int c = 0; c < 8; ++c) {
            int i = c * 256 + t;    // entry in [0,2048); per wave: kgg uniform, el contiguous
            unsigned short* lp = lds + (size_t)(p * 2048 + c * 256 + (t & ~63)) * 8;
            const unsigned short* gp;
            if (c < 4) {
                int kgg = i >> 8, el = i & 255;
                gp = u_g + ((size_t)(ts * 4 + kgg) * E + (e0 + el)) * 8;
            } else {
                int i2 = i - 1024; int kgg = i2 >> 8, el = i2 & 255;
                gp = h_g + ((size_t)(ts * 4 + kgg) * E + (e0 + el)) * 8;
            }
            gl_lds16(gp, lp);
        }
    };
    auto stage_w = [&](int ts) {
        #pragma unroll
        for (int c = 0; c < 3; ++c) {
            int i = c * 256 + t;    // entry in [0,768)
            unsigned short* lp = lds + (size_t)(4096 + c * 256 + (t & ~63)) * 8;
            const unsigned short* gp = wsl + ((size_t)ts * 768 + i) * 8;
            gl_lds16(gp, lp);
        }
    };
    auto compute = [&](int p) {
        bf16x8 au[4], ah[4];
        #pragma unroll
        for (int m = 0; m < 4; ++m) {
            int ea = p * 2048 + kg * 256 + EB + m * 16 + li;
            au[m] = *(bf16x8*)(lds + (size_t)ea * 8);
            ah[m] = *(bf16x8*)(lds + (size_t)(1024 + ea) * 8);
        }
        const unsigned short* W = lds + (size_t)4096 * 8;
        #pragma unroll
        for (int f = 0; f < 2; ++f) {
            int cs = (f * 16 + li) ^ kg;
            bf16x8 bir = *(bf16x8*)(W + ((size_t)(0 * 4 + kg) * 32 + cs) * 8);
            bf16x8 biz = *(bf16x8*)(W + ((size_t)(1 * 4 + kg) * 32 + cs) * 8);
            bf16x8 bin = *(bf16x8*)(W + ((size_t)(2 * 4 + kg) * 32 + cs) * 8);
            bf16x8 bhr = *(bf16x8*)(W + ((size_t)(3 * 4 + kg) * 32 + cs) * 8);
            bf16x8 bhz = *(bf16x8*)(W + ((size_t)(4 * 4 + kg) * 32 + cs) * 8);
            bf16x8 bhn = *(bf16x8*)(W + ((size_t)(5 * 4 + kg) * 32 + cs) * 8);
            #pragma unroll
            for (int m = 0; m < 4; ++m) {
                acc[0][m][f] = __builtin_amdgcn_mfma_f32_16x16x32_bf16(au[m], bir, acc[0][m][f], 0, 0, 0);
                acc[0][m][f] = __builtin_amdgcn_mfma_f32_16x16x32_bf16(ah[m], bhr, acc[0][m][f], 0, 0, 0);
                acc[1][m][f] = __builtin_amdgcn_mfma_f32_16x16x32_bf16(au[m], biz, acc[1][m][f], 0, 0, 0);
                acc[1][m][f] = __builtin_amdgcn_mfma_f32_16x16x32_bf16(ah[m], bhz, acc[1][m][f], 0, 0, 0);
                acc[2][m][f] = __builtin_amdgcn_mfma_f32_16x16x32_bf16(au[m], bin, acc[2][m][f], 0, 0, 0);
                acc[3][m][f] = __builtin_amdgcn_mfma_f32_16x16x32_bf16(ah[m], bhn, acc[3][m][f], 0, 0, 0);
            }
        }
    };

    // prologue: tile 0 in flight (11 ops/thread)
    stage_a(0, 0);
    stage_w(0);

    for (int ts = 0; ts < 15; ++ts) {
        int p = ts & 1;
        stage_a(ts + 1, p ^ 1);                     // +8 in flight
        // FIFO: A(ts)[8], W(ts)[3], A(ts+1)[8] -> wait for first 11
        asm volatile("s_waitcnt vmcnt(8)" ::: "memory");
        __builtin_amdgcn_s_barrier();
        compute(p);
        asm volatile("" ::: "memory");
        __builtin_amdgcn_s_barrier();               // all waves done with W(ts) + bufA[p]
        stage_w(ts + 1);                            // +3 in flight
    }
    asm volatile("s_waitcnt vmcnt(0)" ::: "memory");
    __builtin_amdgcn_s_barrier();
    compute(1);                                     // ts = 15

    // epilogue: gates f32
    #pragma unroll
    for (int f = 0; f < 2; ++f) {
        int c = cb * 32 + f * 16 + li;
        float br = b_ih[c] + b_hh[c];
        float bz = b_ih[c + 512] + b_hh[c + 512];
        float bi = b_ih[c + 1024];
        float bh = b_hh[c + 1024];
        #pragma unroll
        for (int m = 0; m < 4; ++m) {
            #pragma unroll
            for (int q = 0; q < 4; ++q) {
                size_t ge = (size_t)(e0 + EB + m * 16 + kg * 4 + q);
                float r = 1.f / (1.f + __expf(-(acc[0][m][f][q] + br)));
                float z = 1.f / (1.f + __expf(-(acc[1][m][f][q] + bz)));
                float n = tanhf(acc[2][m][f][q] + bi + r * (acc[3][m][f][q] + bh));
                float hp = cur[ge * 512 + c];
                nxt[ge * 512 + c] = (1.f - z) * n + z * hp;
            }
        }
    }
}

// ---------------- MFMA MLP (LN + fc1 + relu + fc2 + residual + h_g + fused next-alpha) --------
__global__ __launch_bounds__(256, 2) void mlp_mfma(
    float* __restrict__ slots,
    const unsigned short* __restrict__ B1img, const unsigned short* __restrict__ B2img,
    const float* __restrict__ lnw, const float* __restrict__ lnb,
    const float* __restrict__ fc1b, const float* __restrict__ fc2b,
    unsigned short* __restrict__ h_g, int write_hg,
    const float* __restrict__ lnsw, const float* __restrict__ lnsb,
    const float* __restrict__ vb, const int* __restrict__ eidx,
    float* __restrict__ alpha_out, unsigned* __restrict__ segmax) {

    __shared__ unsigned short A1[4096];    // frag tile, later reused as [row64][d64] bf16
    __shared__ unsigned short Bst[8192];   // weight staging chunk 16 KB
    __shared__ unsigned short Y1[16384];   // 32 KB

    int t = threadIdx.x;
    int lane = t & 63, wid = t >> 6;
    int li = lane & 15, kg = lane >> 4;
    size_t p0 = (size_t)blockIdx.x * 64;

    // ---- phase 0: load rows, LN (4 threads/row), bf16 A1 tile ----
    {
        int r = t >> 2, c0 = (t & 3) * 16;
        const float* rowp = slots + (p0 + r) * 64 + c0;
        float4 x0 = ((const float4*)rowp)[0];
        float4 x1 = ((const float4*)rowp)[1];
        float4 x2 = ((const float4*)rowp)[2];
        float4 x3 = ((const float4*)rowp)[3];
        float s = x0.x + x0.y + x0.z + x0.w + x1.x + x1.y + x1.z + x1.w
                + x2.x + x2.y + x2.z + x2.w + x3.x + x3.y + x3.z + x3.w;
        s += __shfl_xor(s, 1, 64); s += __shfl_xor(s, 2, 64);
        float m = s * (1.f / 64.f);
        float xv[16] = {x0.x, x0.y, x0.z, x0.w, x1.x, x1.y, x1.z, x1.w,
                        x2.x, x2.y, x2.z, x2.w, x3.x, x3.y, x3.z, x3.w};
        float sq = 0.f;
        #pragma unroll
        for (int i = 0; i < 16; ++i) { float dd = xv[i] - m; sq += dd * dd; }
        sq += __shfl_xor(sq, 1, 64); sq += __shfl_xor(sq, 2, 64);
        float rs = rsqrtf(sq * (1.f / 64.f) + 1e-5f);
        unsigned short u[16];
        #pragma unroll
        for (int i = 0; i < 16; ++i)
            u[i] = f2bf((xv[i] - m) * rs * lnw[c0 + i] + lnb[c0 + i]);
        int g0 = (t & 3) * 2, g1 = g0 + 1;
        *(bf16x8*)(A1 + g0 * 512 + ((r * 8) ^ ((g0 & 3) * 8))) = *(bf16x8*)&u[0];
        *(bf16x8*)(A1 + g1 * 512 + ((r * 8) ^ ((g1 & 3) * 8))) = *(bf16x8*)&u[8];
    }
    __syncthreads();

    // ---- fc1 (swapped): acc1[ct][rt] ----
    f32x4 acc1[4][4] = {};
    #pragma unroll
    for (int kt = 0; kt < 2; ++kt) {
        {   // stage 16KB chunk of B1img via global_load_lds
            #pragma unroll
            for (int c = 0; c < 4; ++c) {
                int i = c * 256 + t;
                gl_lds16(B1img + (size_t)kt * 8192 + (size_t)i * 8,
                         Bst + (size_t)(c * 256 + (t & ~63)) * 8);
            }
        }
        __syncthreads();
        bf16x8 bfrag[4];
        #pragma unroll
        for (int rt = 0; rt < 4; ++rt)
            bfrag[rt] = *(bf16x8*)(A1 + (kt * 4 + kg) * 512 + (((rt * 16 + li) * 8) ^ (kg * 8)));
        #pragma unroll
        for (int ct = 0; ct < 4; ++ct) {
            bf16x8 af = *(bf16x8*)(Bst + kg * 2048 + (((wid * 64 + ct * 16 + li) ^ kg) * 8));
            #pragma unroll
            for (int rt = 0; rt < 4; ++rt)
                acc1[ct][rt] = __builtin_amdgcn_mfma_f32_16x16x32_bf16(af, bfrag[rt], acc1[ct][rt], 0, 0, 0);
        }
        __syncthreads();
    }

    // ---- bias + relu + bf16, packed b64 writes into Y1 ----
    #pragma unroll
    for (int ct = 0; ct < 4; ++ct) {
        int c0 = wid * 64 + ct * 16 + kg * 4;
        float4 b1 = *(const float4*)(fc1b + c0);
        int g = c0 >> 3;
        #pragma unroll
        for (int rt = 0; rt < 4; ++rt) {
            f32x4 vv = acc1[ct][rt];
            float y0 = fmaxf(vv[0] + b1.x, 0.f), y1v = fmaxf(vv[1] + b1.y, 0.f);
            float y2 = fmaxf(vv[2] + b1.z, 0.f), y3 = fmaxf(vv[3] + b1.w, 0.f);
            unsigned lo = (unsigned)f2bf(y0) | ((unsigned)f2bf(y1v) << 16);
            unsigned hi = (unsigned)f2bf(y2) | ((unsigned)f2bf(y3) << 16);
            int r = rt * 16 + li;
            int off = g * 512 + ((r * 8) ^ ((g & 3) * 8)) + (c0 & 7);
            uint2 pk; pk.x = lo; pk.y = hi;
            *(uint2*)(Y1 + off) = pk;
        }
    }
    __syncthreads();

    // ---- fc2 ----
    f32x4 acc2[4] = {};
    #pragma unroll
    for (int hc = 0; hc < 2; ++hc) {
        {   // stage 16KB chunk of B2img via global_load_lds
            #pragma unroll
            for (int c = 0; c < 4; ++c) {
                int i = c * 256 + t;
                gl_lds16(B2img + (size_t)hc * 8192 + (size_t)i * 8,
                         Bst + (size_t)(c * 256 + (t & ~63)) * 8);
            }
        }
        __syncthreads();
        #pragma unroll
        for (int ktl = 0; ktl < 4; ++ktl) {
            int ktg = hc * 4 + ktl;
            bf16x8 af = *(bf16x8*)(Y1 + (ktg * 4 + kg) * 512 + (((wid * 16 + li) * 8) ^ (kg * 8)));
            #pragma unroll
            for (int nt = 0; nt < 4; ++nt) {
                bf16x8 bf = *(bf16x8*)(Bst + (ktl * 4 + kg) * 512 + (((nt * 16 + li) ^ kg) * 8));
                acc2[nt] = __builtin_amdgcn_mfma_f32_16x16x32_bf16(af, bf, acc2[nt], 0, 0, 0);
            }
        }
        __syncthreads();
    }

    // ---- epilogue: residual add in-place; stash bf16 into A1; keep f32 vals ----
    float vals[4][4];   // [nt][q] : row r = wid*16+kg*4+q, col d = nt*16+li
    #pragma unroll
    for (int nt = 0; nt < 4; ++nt) {
        int dd = nt * 16 + li;
        float b2 = fc2b[dd];
        #pragma unroll
        for (int q = 0; q < 4; ++q) {
            int r = wid * 16 + kg * 4 + q;
            size_t gp = (p0 + r) * 64 + dd;
            float val = slots[gp] + acc2[nt][q] + b2;
            slots[gp] = val;
            A1[r * 64 + dd] = f2bf(val);
            vals[nt][q] = val;
        }
    }
    if (write_hg) {
        // ---- fused alpha for next iteration (f32-exact LN_slots + v_h dot + leaky) ----
        #pragma unroll
        for (int q = 0; q < 4; ++q) {
            int r = wid * 16 + kg * 4 + q;
            float s = vals[0][q] + vals[1][q] + vals[2][q] + vals[3][q];
            s += __shfl_xor(s, 1, 64); s += __shfl_xor(s, 2, 64);
            s += __shfl_xor(s, 4, 64); s += __shfl_xor(s, 8, 64);
            float mean = s * (1.f / 64.f);
            float sq = 0.f;
            #pragma unroll
            for (int nt = 0; nt < 4; ++nt) { float d = vals[nt][q] - mean; sq += d * d; }
            sq += __shfl_xor(sq, 1, 64); sq += __shfl_xor(sq, 2, 64);
            sq += __shfl_xor(sq, 4, 64); sq += __shfl_xor(sq, 8, 64);
            float rs = rsqrtf(sq * (1.f / 64.f) + 1e-5f);
            int h = r & 7;
            float dp = 0.f;
            #pragma unroll
            for (int nt = 0; nt < 4; ++nt) {
                int dd = nt * 16 + li;
                float ln = (vals[nt][q] - mean) * rs * lnsw[dd] + lnsb[dd];
                dp += ln * vb[h * 64 + dd];
            }
            dp += __shfl_xor(dp, 1, 64); dp += __shfl_xor(dp, 2, 64);
            dp += __shfl_xor(dp, 4, 64); dp += __shfl_xor(dp, 8, 64);
            if (li == 0) {
                float a = dp * 0.125f;
                a = a >= 0.f ? a : 0.2f * a;
                size_t p = p0 + r;
                alpha_out[p] = a;
                int e = (int)(p >> 3);
                unsigned b = __float_as_uint(a);
                unsigned enc = (b & 0x80000000u) ? ~b : (b | 0x80000000u);
                atomicMax(&segmax[eidx[e] * 8 + h], enc);
            }
        }
        __syncthreads();
        #pragma unroll
        for (int c2 = 0; c2 < 2; ++c2) {
            int n = c2 * 256 + t;           // 0..511 = (h*8+g)*8 + eloc
            int eloc = n & 7;
            int hg8 = n >> 3;
            int hh = hg8 >> 3, g = hg8 & 7;
            int r = eloc * 8 + hh;
            bf16x8 v = *(bf16x8*)(A1 + r * 64 + g * 8);
            int k = hh * 64 + g * 8;
            int tt = k >> 5, kgg = (k >> 3) & 3;
            size_t e = (size_t)blockIdx.x * 8 + eloc;
            *(bf16x8*)(h_g + ((size_t)(tt * 4 + kgg) * E + e) * 8) = v;
        }
    }
}

extern "C" void kernel_launch(void* const* d_in, const int* in_sizes, int n_in,
                              void* d_out, int out_size, void* d_ws, size_t ws_size,
                              hipStream_t stream) {
    const float* x     = (const float*)d_in[0];
    const int*   eidx  = (const int*)d_in[1];
    const float* nd    = (const float*)d_in[3];
    const float* mu    = (const float*)d_in[4];
    const float* lsig  = (const float*)d_in[5];
    const float* atten = (const float*)d_in[6];
    const float* ln_sw = (const float*)d_in[7];
    const float* ln_sb = (const float*)d_in[8];
    const float* ln_mw = (const float*)d_in[9];
    const float* ln_mb = (const float*)d_in[10];
    const float* Wq    = (const float*)d_in[11];
    const float* Wk    = (const float*)d_in[12];
    const float* w_ih  = (const float*)d_in[13];
    const float* w_hh  = (const float*)d_in[14];
    const float* b_ih  = (const float*)d_in[15];
    const float* b_hh  = (const float*)d_in[16];
    const float* fc1w  = (const float*)d_in[17];
    const float* fc1b  = (const float*)d_in[18];
    const float* fc2w  = (const float*)d_in[19];
    const float* fc2b  = (const float*)d_in[20];

    float* out = (float*)d_out;
    char* ws = (char*)d_ws;
    size_t off = 0;
    auto alloc = [&](size_t nbytes) {
        void* p = ws + off;
        off += (nbytes + 255) & ~(size_t)255;
        return p;
    };
    float*          slotsA = (float*)alloc((size_t)E * HD * 4);
    float*          kbuf   = (float*)alloc((size_t)E * 64 * 4);
    float*          alpha  = (float*)alloc((size_t)E * 8 * 4);
    unsigned*       segmax = (unsigned*)alloc((size_t)Nn * 8 * 4);
    float*          segsum = (float*)alloc((size_t)Nn * 8 * 4);
    float*          vbuf   = (float*)alloc(512 * 4);
    unsigned short* B1img  = (unsigned short*)alloc(16384 * 2);
    unsigned short* B2img  = (unsigned short*)alloc(16384 * 2);
    unsigned short* wb     = (unsigned short*)alloc((size_t)1572864 * 2);
    unsigned short* u_g    = (unsigned short*)alloc((size_t)E * HD * 2);
    unsigned short* h_g    = (unsigned short*)alloc((size_t)E * HD * 2);

    const int GRU_LDS_BYTES = 4864 * 16;   // 76 KB dynamic LDS
    hipFuncSetAttribute((const void*)gru_mfma,
                        hipFuncAttributeMaxDynamicSharedMemorySize, GRU_LDS_BYTES);

    prep_v<<<1, 512, 0, stream>>>(atten, Wq, vbuf);
    prep_mlp<<<128, 256, 0, stream>>>(fc1w, fc2w, B1img, B2img);
    wprep<<<6144, 256, 0, stream>>>(w_ih, w_hh, wb);
    compute_k<<<4096, 256, 0, stream>>>(x, Wk, kbuf);
    init_slots<<<2048, 256, 0, stream>>>(nd, mu, lsig, slotsA, h_g);

    // iteration-0 alpha (later iterations: fused into mlp_mfma)
    seg_init<<<512, 256, 0, stream>>>(segmax, segsum);
    alpha_ln<<<E * 8 / 4, 256, 0, stream>>>(slotsA, vbuf, ln_sw, ln_sb, eidx, alpha, segmax);

    float* cur = slotsA;
    float* nxt = out;
    for (int it = 0; it < 3; ++it) {
        exp_sum<<<E * 8 / 256, 256, 0, stream>>>(eidx, segmax, alpha, segsum);
        prep_u<<<E / 256, 256, 0, stream>>>(kbuf, alpha, segsum, eidx, u_g);
        gru_mfma<<<16384, 256, GRU_LDS_BYTES, stream>>>(cur, u_g, h_g, wb, b_ih, b_hh, nxt);
        if (it < 2)
            seg_init<<<512, 256, 0, stream>>>(segmax, segsum);
        mlp_mfma<<<32768, 256, 0, stream>>>(nxt, B1img, B2img, ln_mw, ln_mb, fc1b, fc2b,
                                            h_g, (it < 2) ? 1 : 0,
                                            ln_sw, ln_sb, vbuf, eidx, alpha, segmax);
        float* tmp = cur; cur = nxt; nxt = tmp;
    }
    (void)in_sizes; (void)n_in; (void)out_size; (void)ws_size;
}

// Round 8
// 6658.514 us; speedup vs baseline: 1.1946x; 1.0921x over previous
//
#include <hip/hip_runtime.h>
#include <math.h>

#define E 262144
#define Nn 16384
#define H 8
#define D 64
#define HD 512
#define HID 256

typedef float f32x4 __attribute__((ext_vector_type(4)));
typedef short bf16x8 __attribute__((ext_vector_type(8)));

__device__ __forceinline__ float wave_sum(float v) {
    #pragma unroll
    for (int m = 1; m < 64; m <<= 1) v += __shfl_xor(v, m, 64);
    return v;
}

__device__ __forceinline__ unsigned short f2bf(float f) {
    unsigned u = __float_as_uint(f);
    return (unsigned short)((u + 0x7fffu + ((u >> 16) & 1u)) >> 16);
}

__device__ __forceinline__ float bf2f(unsigned short u) {
    return __uint_as_float((unsigned)u << 16);
}

__device__ __forceinline__ void gl_lds16(const void* g, void* l) {
    __builtin_amdgcn_global_load_lds(
        (const __attribute__((address_space(1))) void*)g,
        (__attribute__((address_space(3))) void*)l, 16, 0, 0);
}

// v[h][j] = sum_d atten[h][d] * Wq[d][j]
__global__ void prep_v(const float* __restrict__ atten, const float* __restrict__ Wq,
                       float* __restrict__ v) {
    int t = threadIdx.x;            // 512 threads
    int h = t >> 6, j = t & 63;
    float a = 0.f;
    #pragma unroll 8
    for (int d = 0; d < 64; ++d) a += atten[h * 64 + d] * Wq[d * 64 + j];
    v[h * 64 + j] = a;
}

// MLP weight images (bf16, MFMA-frag layout, kg-XOR bank swizzle baked in)
__global__ void prep_mlp(const float* __restrict__ fc1w, const float* __restrict__ fc2w,
                         unsigned short* __restrict__ B1img, unsigned short* __restrict__ B2img) {
    int i = blockIdx.x * 256 + threadIdx.x;   // 32768 total
    if (i < 16384) {
        int j = i & 7, g = i >> 3;
        int cs = g & 255, kgkt = g >> 8;
        int kg = kgkt & 3, kt = kgkt >> 2;
        int c = cs ^ kg;
        int k = kt * 32 + kg * 8 + j;
        B1img[i] = f2bf(fc1w[c * 64 + k]);
    } else {
        int i2 = i - 16384;
        int j = i2 & 7, g = i2 >> 3;
        int ds = g & 63, kgkt = g >> 6;
        int kg = kgkt & 3, kt = kgkt >> 2;
        int dd = ds ^ kg;
        int c = kt * 32 + kg * 8 + j;
        B2img[i2] = f2bf(fc2w[dd * 256 + c]);
    }
}

// GRU weights bf16 image for BN=32:
// wb[cb(16)][t(16)][m(6)][kg(4)][cs(32)][j(8)] = w[(m%3)*512 + cb*32 + (cs^kg)][t*32+kg*8+j]
__global__ void wprep(const float* __restrict__ w_ih, const float* __restrict__ w_hh,
                      unsigned short* __restrict__ wb) {
    int o = blockIdx.x * 256 + threadIdx.x;   // 1,572,864 total
    int slice = o / 6144;
    int w = o - slice * 6144;
    int t = slice & 15, cb = slice >> 4;
    int j = w & 7;
    int cs = (w >> 3) & 31;
    int kgm = w >> 8;
    int kg = kgm & 3, m = kgm >> 2;
    const float* wm = (m < 3) ? w_ih : w_hh;
    int row = (m % 3) * 512 + cb * 32 + (cs ^ kg);
    int k = t * 32 + kg * 8 + j;
    wb[o] = f2bf(wm[(size_t)row * 512 + k]);
}

// k[e][d] = 0.125 * sum_j x[e][j] * Wk[d][j]
__global__ __launch_bounds__(256) void compute_k(const float* __restrict__ x,
                                                 const float* __restrict__ Wk,
                                                 float* __restrict__ kbuf) {
    __shared__ float sWk[64][130];
    int t = threadIdx.x;
    for (int i = t; i < 64 * 128; i += 256) sWk[i >> 7][i & 127] = Wk[i];
    __syncthreads();
    int lane = t & 63, w = t >> 6;
    for (int e = blockIdx.x * 4 + w; e < E; e += gridDim.x * 4) {
        const float* xr = x + (size_t)e * 128;
        float acc = 0.f;
        #pragma unroll 8
        for (int j = 0; j < 128; ++j) acc += xr[j] * sWk[lane][j];
        kbuf[(size_t)e * 64 + lane] = acc * 0.125f;
    }
}

// slots = mu + exp(log_sigma) * norm_dist ; also emit bf16 h_g image
__global__ void init_slots(const float* __restrict__ nd, const float* __restrict__ mu,
                           const float* __restrict__ lsig, float* __restrict__ out,
                           unsigned short* __restrict__ h_g) {
    __shared__ float sMu[64], sSig[64];
    if (threadIdx.x < 64) {
        sMu[threadIdx.x]  = mu[threadIdx.x];
        sSig[threadIdx.x] = __expf(lsig[threadIdx.x]);
    }
    __syncthreads();
    size_t n4 = (size_t)E * HD / 4;
    size_t stride = (size_t)gridDim.x * blockDim.x;
    for (size_t i = (size_t)blockIdx.x * blockDim.x + threadIdx.x; i < n4; i += stride) {
        float4 v = ((const float4*)nd)[i];
        size_t flat = i * 4;
        int d0 = (int)(flat & 63);
        v.x = sMu[d0]     + sSig[d0]     * v.x;
        v.y = sMu[d0 + 1] + sSig[d0 + 1] * v.y;
        v.z = sMu[d0 + 2] + sSig[d0 + 2] * v.z;
        v.w = sMu[d0 + 3] + sSig[d0 + 3] * v.w;
        ((float4*)out)[i] = v;
        int e = (int)(flat >> 9);
        int k = (int)(flat & 511);
        int tt = k >> 5, kgg = (k >> 3) & 3, jo = k & 7;  // jo in {0,4}
        uint2 pk;
        pk.x = (unsigned)f2bf(v.x) | ((unsigned)f2bf(v.y) << 16);
        pk.y = (unsigned)f2bf(v.z) | ((unsigned)f2bf(v.w) << 16);
        *(uint2*)(h_g + ((size_t)(tt * 4 + kgg) * E + e) * 8 + jo) = pk;
    }
}

__global__ void seg_init(unsigned* __restrict__ segmax, float* __restrict__ segsum) {
    int i = blockIdx.x * 256 + threadIdx.x;
    if (i < Nn * H) { segmax[i] = 0u; segsum[i] = 0.f; }
}

// one wave per (e,h): LN(slots row) -> dot v_h -> leaky_relu -> alpha ; atomicMax into segmax
// (used once, for iteration 0; later iterations fuse this into mlp_mfma's epilogue)
__global__ __launch_bounds__(256) void alpha_ln(const float* __restrict__ cur,
                                                const float* __restrict__ v,
                                                const float* __restrict__ lnw,
                                                const float* __restrict__ lnb,
                                                const int* __restrict__ eidx,
                                                float* __restrict__ alpha,
                                                unsigned* __restrict__ segmax) {
    int lane = threadIdx.x & 63, w = threadIdx.x >> 6;
    size_t p = (size_t)blockIdx.x * 4 + w;          // grid = E*H/4 exactly
    float x = cur[p * 64 + lane];
    float m = wave_sum(x) * (1.f / 64.f);
    float d = x - m;
    float var = wave_sum(d * d) * (1.f / 64.f);
    float rs = rsqrtf(var + 1e-5f);
    float ln = d * rs * lnw[lane] + lnb[lane];
    int h = (int)(p & 7);
    float dot = wave_sum(ln * v[h * 64 + lane]) * 0.125f;
    float a = dot >= 0.f ? dot : 0.2f * dot;
    if (lane == 0) {
        alpha[p] = a;
        int e = (int)(p >> 3);
        int id = eidx[e];
        unsigned b = __float_as_uint(a);
        unsigned enc = (b & 0x80000000u) ? ~b : (b | 0x80000000u);
        atomicMax(&segmax[id * 8 + h], enc);
    }
}

__global__ void exp_sum(const int* __restrict__ eidx, const unsigned* __restrict__ segmax,
                        float* __restrict__ alpha, float* __restrict__ segsum) {
    size_t p = (size_t)blockIdx.x * 256 + threadIdx.x;
    int e = (int)(p >> 3), h = (int)(p & 7);
    int id = eidx[e];
    unsigned u = segmax[id * 8 + h];
    float m = __uint_as_float((u & 0x80000000u) ? (u & 0x7fffffffu) : ~u);
    float val = __expf(alpha[p] - m);
    alpha[p] = val;
    atomicAdd(&segsum[id * 8 + h], val);
}

// normalize alpha + build u_g = bf16((k*alpha)) in [t][kg][E][8] layout. thread per edge.
__global__ __launch_bounds__(256) void prep_u(const float* __restrict__ kbuf,
                                              const float* __restrict__ alpha,
                                              const float* __restrict__ segsum,
                                              const int* __restrict__ eidx,
                                              unsigned short* __restrict__ u_g) {
    int e = blockIdx.x * 256 + threadIdx.x;
    int id = eidx[e];
    float a[8];
    #pragma unroll
    for (int h = 0; h < 8; ++h)
        a[h] = alpha[(size_t)e * 8 + h] / (segsum[id * 8 + h] + 1e-16f);
    float4 kv[16];
    const float4* kr = (const float4*)(kbuf + (size_t)e * 64);
    #pragma unroll
    for (int q = 0; q < 16; ++q) kv[q] = kr[q];
    const float* kf = (const float*)kv;
    #pragma unroll
    for (int tt = 0; tt < 16; ++tt) {
        float ah = a[tt >> 1];
        #pragma unroll
        for (int kg = 0; kg < 4; ++kg) {
            int dbase = (tt & 1) * 32 + kg * 8;
            bf16x8 v;
            #pragma unroll
            for (int j = 0; j < 8; ++j) v[j] = (short)f2bf(kf[dbase + j] * ah);
            *(bf16x8*)(u_g + ((size_t)(tt * 4 + kg) * E + e) * 8) = v;
        }
    }
}

// ---------------- MFMA GRU : BM=256 x BN=32, BK=32, dbuf-A + counted vmcnt ----------------
// Round-5 block map (best measured). hprev read from h_g (bf16) -> cur not touched.
__global__ __launch_bounds__(256, 2) void gru_mfma(
    const unsigned short* __restrict__ u_g, const unsigned short* __restrict__ h_g,
    const unsigned short* __restrict__ wb,
    const float* __restrict__ b_ih, const float* __restrict__ b_hh,
    float* __restrict__ nxt) {

    extern __shared__ unsigned short lds[];

    int bid = blockIdx.x;
    int lbid = (bid & 7) * 2048 + (bid >> 3);   // XCD-contiguous chunks (16384 % 8 == 0)
    int eb = lbid >> 4, cb = lbid & 15;
    int e0 = eb * 256;
    int t = threadIdx.x;
    int lane = t & 63, wid = t >> 6;
    int li = lane & 15, kg = lane >> 4;
    int EB = wid * 64;

    const unsigned short* wsl = wb + (size_t)(cb * 16) * 6144;

    f32x4 acc[4][4][2] = {};   // [plane][m][f]

    auto stage_a = [&](int ts, int p) {
        #pragma unroll
        for (int c = 0; c < 8; ++c) {
            int i = c * 256 + t;
            unsigned short* lp = lds + (size_t)(p * 2048 + c * 256 + (t & ~63)) * 8;
            const unsigned short* gp;
            if (c < 4) {
                int kgg = i >> 8, el = i & 255;
                gp = u_g + ((size_t)(ts * 4 + kgg) * E + (e0 + el)) * 8;
            } else {
                int i2 = i - 1024; int kgg = i2 >> 8, el = i2 & 255;
                gp = h_g + ((size_t)(ts * 4 + kgg) * E + (e0 + el)) * 8;
            }
            gl_lds16(gp, lp);
        }
    };
    auto stage_w = [&](int ts) {
        #pragma unroll
        for (int c = 0; c < 3; ++c) {
            int i = c * 256 + t;
            unsigned short* lp = lds + (size_t)(4096 + c * 256 + (t & ~63)) * 8;
            const unsigned short* gp = wsl + ((size_t)ts * 768 + i) * 8;
            gl_lds16(gp, lp);
        }
    };
    auto compute = [&](int p) {
        bf16x8 au[4], ah[4];
        #pragma unroll
        for (int m = 0; m < 4; ++m) {
            int ea = p * 2048 + kg * 256 + EB + m * 16 + li;
            au[m] = *(bf16x8*)(lds + (size_t)ea * 8);
            ah[m] = *(bf16x8*)(lds + (size_t)(1024 + ea) * 8);
        }
        const unsigned short* W = lds + (size_t)4096 * 8;
        #pragma unroll
        for (int f = 0; f < 2; ++f) {
            int cs = (f * 16 + li) ^ kg;
            bf16x8 bir = *(bf16x8*)(W + ((size_t)(0 * 4 + kg) * 32 + cs) * 8);
            bf16x8 biz = *(bf16x8*)(W + ((size_t)(1 * 4 + kg) * 32 + cs) * 8);
            bf16x8 bin = *(bf16x8*)(W + ((size_t)(2 * 4 + kg) * 32 + cs) * 8);
            bf16x8 bhr = *(bf16x8*)(W + ((size_t)(3 * 4 + kg) * 32 + cs) * 8);
            bf16x8 bhz = *(bf16x8*)(W + ((size_t)(4 * 4 + kg) * 32 + cs) * 8);
            bf16x8 bhn = *(bf16x8*)(W + ((size_t)(5 * 4 + kg) * 32 + cs) * 8);
            #pragma unroll
            for (int m = 0; m < 4; ++m) {
                acc[0][m][f] = __builtin_amdgcn_mfma_f32_16x16x32_bf16(au[m], bir, acc[0][m][f], 0, 0, 0);
                acc[0][m][f] = __builtin_amdgcn_mfma_f32_16x16x32_bf16(ah[m], bhr, acc[0][m][f], 0, 0, 0);
                acc[1][m][f] = __builtin_amdgcn_mfma_f32_16x16x32_bf16(au[m], biz, acc[1][m][f], 0, 0, 0);
                acc[1][m][f] = __builtin_amdgcn_mfma_f32_16x16x32_bf16(ah[m], bhz, acc[1][m][f], 0, 0, 0);
                acc[2][m][f] = __builtin_amdgcn_mfma_f32_16x16x32_bf16(au[m], bin, acc[2][m][f], 0, 0, 0);
                acc[3][m][f] = __builtin_amdgcn_mfma_f32_16x16x32_bf16(ah[m], bhn, acc[3][m][f], 0, 0, 0);
            }
        }
    };

    // prologue: tile 0 in flight (11 ops/thread)
    stage_a(0, 0);
    stage_w(0);

    for (int ts = 0; ts < 15; ++ts) {
        int p = ts & 1;
        stage_a(ts + 1, p ^ 1);                     // +8 in flight
        asm volatile("s_waitcnt vmcnt(8)" ::: "memory");
        __builtin_amdgcn_s_barrier();
        compute(p);
        asm volatile("" ::: "memory");
        __builtin_amdgcn_s_barrier();               // all waves done with W(ts) + bufA[p]
        stage_w(ts + 1);                            // +3 in flight
    }
    asm volatile("s_waitcnt vmcnt(0)" ::: "memory");
    __builtin_amdgcn_s_barrier();
    compute(1);                                     // ts = 15

    // epilogue: gates f32, hprev from h_g (bf16)
    #pragma unroll
    for (int f = 0; f < 2; ++f) {
        int c = cb * 32 + f * 16 + li;
        float br = b_ih[c] + b_hh[c];
        float bz = b_ih[c + 512] + b_hh[c + 512];
        float bi = b_ih[c + 1024];
        float bh = b_hh[c + 1024];
        size_t hb = (size_t)(c >> 3) * E * 8 + (c & 7);
        #pragma unroll
        for (int m = 0; m < 4; ++m) {
            #pragma unroll
            for (int q = 0; q < 4; ++q) {
                size_t ge = (size_t)(e0 + EB + m * 16 + kg * 4 + q);
                float r = 1.f / (1.f + __expf(-(acc[0][m][f][q] + br)));
                float z = 1.f / (1.f + __expf(-(acc[1][m][f][q] + bz)));
                float n = tanhf(acc[2][m][f][q] + bi + r * (acc[3][m][f][q] + bh));
                float hp = bf2f(h_g[hb + ge * 8]);
                nxt[ge * 512 + c] = (1.f - z) * n + z * hp;
            }
        }
    }
}

// ---------------- MFMA MLP : async-staged dbuf weights + LN + fc1/relu/fc2 + alpha ----------
// dynamic LDS (ushorts): A1 [0,4096) | Bs0 [4096,12288) | Bs1 [12288,20480) | Y1 [20480,36864)
__global__ __launch_bounds__(256, 2) void mlp_mfma(
    float* __restrict__ slots,
    const unsigned short* __restrict__ B1img, const unsigned short* __restrict__ B2img,
    const float* __restrict__ lnw, const float* __restrict__ lnb,
    const float* __restrict__ fc1b, const float* __restrict__ fc2b,
    unsigned short* __restrict__ h_g, int write_hg,
    const float* __restrict__ lnsw, const float* __restrict__ lnsb,
    const float* __restrict__ vb, const int* __restrict__ eidx,
    float* __restrict__ alpha_out, unsigned* __restrict__ segmax) {

    extern __shared__ unsigned short mlds[];
    unsigned short* A1  = mlds;
    unsigned short* Bs0 = mlds + 4096;
    unsigned short* Bs1 = mlds + 12288;
    unsigned short* Y1  = mlds + 20480;

    int t = threadIdx.x;
    int lane = t & 63, wid = t >> 6;
    int li = lane & 15, kg = lane >> 4;
    size_t p0 = (size_t)blockIdx.x * 64;

    auto stg = [&](const unsigned short* src, unsigned short* dst) {
        #pragma unroll
        for (int c = 0; c < 4; ++c) {
            int i = c * 256 + t;
            gl_lds16(src + (size_t)i * 8, dst + (size_t)(c * 256 + (t & ~63)) * 8);
        }
    };

    stg(B1img, Bs0);                                   // B1.0 in flight

    // ---- phase 0: load rows, LN (4 threads/row), bf16 A1 tile ----
    {
        int r = t >> 2, c0 = (t & 3) * 16;
        const float* rowp = slots + (p0 + r) * 64 + c0;
        float4 x0 = ((const float4*)rowp)[0];
        float4 x1 = ((const float4*)rowp)[1];
        float4 x2 = ((const float4*)rowp)[2];
        float4 x3 = ((const float4*)rowp)[3];
        float s = x0.x + x0.y + x0.z + x0.w + x1.x + x1.y + x1.z + x1.w
                + x2.x + x2.y + x2.z + x2.w + x3.x + x3.y + x3.z + x3.w;
        s += __shfl_xor(s, 1, 64); s += __shfl_xor(s, 2, 64);
        float m = s * (1.f / 64.f);
        float xv[16] = {x0.x, x0.y, x0.z, x0.w, x1.x, x1.y, x1.z, x1.w,
                        x2.x, x2.y, x2.z, x2.w, x3.x, x3.y, x3.z, x3.w};
        float sq = 0.f;
        #pragma unroll
        for (int i = 0; i < 16; ++i) { float dd = xv[i] - m; sq += dd * dd; }
        sq += __shfl_xor(sq, 1, 64); sq += __shfl_xor(sq, 2, 64);
        float rs = rsqrtf(sq * (1.f / 64.f) + 1e-5f);
        unsigned short u[16];
        #pragma unroll
        for (int i = 0; i < 16; ++i)
            u[i] = f2bf((xv[i] - m) * rs * lnw[c0 + i] + lnb[c0 + i]);
        int g0 = (t & 3) * 2, g1 = g0 + 1;
        *(bf16x8*)(A1 + g0 * 512 + ((r * 8) ^ ((g0 & 3) * 8))) = *(bf16x8*)&u[0];
        *(bf16x8*)(A1 + g1 * 512 + ((r * 8) ^ ((g1 & 3) * 8))) = *(bf16x8*)&u[8];
    }

    stg(B1img + 8192, Bs1);                            // B1.1 in flight

    f32x4 acc1[4][4] = {};
    auto fc1c = [&](int kt, const unsigned short* Bs) {
        bf16x8 bfrag[4];
        #pragma unroll
        for (int rt = 0; rt < 4; ++rt)
            bfrag[rt] = *(bf16x8*)(A1 + (kt * 4 + kg) * 512 + (((rt * 16 + li) * 8) ^ (kg * 8)));
        #pragma unroll
        for (int ct = 0; ct < 4; ++ct) {
            bf16x8 af = *(bf16x8*)(Bs + kg * 2048 + (((wid * 64 + ct * 16 + li) ^ kg) * 8));
            #pragma unroll
            for (int rt = 0; rt < 4; ++rt)
                acc1[ct][rt] = __builtin_amdgcn_mfma_f32_16x16x32_bf16(af, bfrag[rt], acc1[ct][rt], 0, 0, 0);
        }
    };

    asm volatile("s_waitcnt vmcnt(4)" ::: "memory");   // Bs0 ready
    __syncthreads();                                   // + A1 visible
    fc1c(0, Bs0);
    __syncthreads();                                   // all done reading Bs0
    stg(B2img, Bs0);                                   // B2.0 in flight
    asm volatile("s_waitcnt vmcnt(4)" ::: "memory");   // Bs1 (B1.1) ready
    __syncthreads();
    fc1c(1, Bs1);

    // ---- bias + relu + bf16, packed b64 writes into Y1 ----
    #pragma unroll
    for (int ct = 0; ct < 4; ++ct) {
        int c0 = wid * 64 + ct * 16 + kg * 4;
        float4 b1 = *(const float4*)(fc1b + c0);
        int g = c0 >> 3;
        #pragma unroll
        for (int rt = 0; rt < 4; ++rt) {
            f32x4 vv = acc1[ct][rt];
            float y0 = fmaxf(vv[0] + b1.x, 0.f), y1v = fmaxf(vv[1] + b1.y, 0.f);
            float y2 = fmaxf(vv[2] + b1.z, 0.f), y3 = fmaxf(vv[3] + b1.w, 0.f);
            unsigned lo = (unsigned)f2bf(y0) | ((unsigned)f2bf(y1v) << 16);
            unsigned hi = (unsigned)f2bf(y2) | ((unsigned)f2bf(y3) << 16);
            int r = rt * 16 + li;
            int off = g * 512 + ((r * 8) ^ ((g & 3) * 8)) + (c0 & 7);
            uint2 pk; pk.x = lo; pk.y = hi;
            *(uint2*)(Y1 + off) = pk;
        }
    }
    __syncthreads();                                   // done reading Bs1, Y1 visible
    stg(B2img + 8192, Bs1);                            // B2.1 in flight

    f32x4 acc2[4] = {};
    auto fc2c = [&](int hc, const unsigned short* Bs) {
        #pragma unroll
        for (int ktl = 0; ktl < 4; ++ktl) {
            int ktg = hc * 4 + ktl;
            bf16x8 af = *(bf16x8*)(Y1 + (ktg * 4 + kg) * 512 + (((wid * 16 + li) * 8) ^ (kg * 8)));
            #pragma unroll
            for (int nt = 0; nt < 4; ++nt) {
                bf16x8 bf = *(bf16x8*)(Bs + (ktl * 4 + kg) * 512 + (((nt * 16 + li) ^ kg) * 8));
                acc2[nt] = __builtin_amdgcn_mfma_f32_16x16x32_bf16(af, bf, acc2[nt], 0, 0, 0);
            }
        }
    };

    asm volatile("s_waitcnt vmcnt(4)" ::: "memory");   // Bs0 (B2.0) ready
    __syncthreads();
    fc2c(0, Bs0);
    asm volatile("s_waitcnt vmcnt(0)" ::: "memory");   // Bs1 (B2.1) ready
    __syncthreads();
    fc2c(1, Bs1);

    // ---- epilogue: residual add in-place; stash bf16 into A1; keep f32 vals ----
    float vals[4][4];   // [nt][q] : row r = wid*16+kg*4+q, col d = nt*16+li
    #pragma unroll
    for (int nt = 0; nt < 4; ++nt) {
        int dd = nt * 16 + li;
        float b2 = fc2b[dd];
        #pragma unroll
        for (int q = 0; q < 4; ++q) {
            int r = wid * 16 + kg * 4 + q;
            size_t gp = (p0 + r) * 64 + dd;
            float val = slots[gp] + acc2[nt][q] + b2;
            slots[gp] = val;
            A1[r * 64 + dd] = f2bf(val);
            vals[nt][q] = val;
        }
    }
    if (write_hg) {
        // ---- fused alpha for next iteration (f32-exact LN_slots + v_h dot + leaky) ----
        #pragma unroll
        for (int q = 0; q < 4; ++q) {
            int r = wid * 16 + kg * 4 + q;
            float s = vals[0][q] + vals[1][q] + vals[2][q] + vals[3][q];
            s += __shfl_xor(s, 1, 64); s += __shfl_xor(s, 2, 64);
            s += __shfl_xor(s, 4, 64); s += __shfl_xor(s, 8, 64);
            float mean = s * (1.f / 64.f);
            float sq = 0.f;
            #pragma unroll
            for (int nt = 0; nt < 4; ++nt) { float d = vals[nt][q] - mean; sq += d * d; }
            sq += __shfl_xor(sq, 1, 64); sq += __shfl_xor(sq, 2, 64);
            sq += __shfl_xor(sq, 4, 64); sq += __shfl_xor(sq, 8, 64);
            float rs = rsqrtf(sq * (1.f / 64.f) + 1e-5f);
            int h = r & 7;
            float dp = 0.f;
            #pragma unroll
            for (int nt = 0; nt < 4; ++nt) {
                int dd = nt * 16 + li;
                float ln = (vals[nt][q] - mean) * rs * lnsw[dd] + lnsb[dd];
                dp += ln * vb[h * 64 + dd];
            }
            dp += __shfl_xor(dp, 1, 64); dp += __shfl_xor(dp, 2, 64);
            dp += __shfl_xor(dp, 4, 64); dp += __shfl_xor(dp, 8, 64);
            if (li == 0) {
                float a = dp * 0.125f;
                a = a >= 0.f ? a : 0.2f * a;
                size_t p = p0 + r;
                alpha_out[p] = a;
                int e = (int)(p >> 3);
                unsigned b = __float_as_uint(a);
                unsigned enc = (b & 0x80000000u) ? ~b : (b | 0x80000000u);
                atomicMax(&segmax[eidx[e] * 8 + h], enc);
            }
        }
        __syncthreads();
        #pragma unroll
        for (int c2 = 0; c2 < 2; ++c2) {
            int n = c2 * 256 + t;           // 0..511 = (h*8+g)*8 + eloc
            int eloc = n & 7;
            int hg8 = n >> 3;
            int hh = hg8 >> 3, g = hg8 & 7;
            int r = eloc * 8 + hh;
            bf16x8 v = *(bf16x8*)(A1 + r * 64 + g * 8);
            int k = hh * 64 + g * 8;
            int tt = k >> 5, kgg = (k >> 3) & 3;
            size_t e = (size_t)blockIdx.x * 8 + eloc;
            *(bf16x8*)(h_g + ((size_t)(tt * 4 + kgg) * E + e) * 8) = v;
        }
    }
}

extern "C" void kernel_launch(void* const* d_in, const int* in_sizes, int n_in,
                              void* d_out, int out_size, void* d_ws, size_t ws_size,
                              hipStream_t stream) {
    const float* x     = (const float*)d_in[0];
    const int*   eidx  = (const int*)d_in[1];
    const float* nd    = (const float*)d_in[3];
    const float* mu    = (const float*)d_in[4];
    const float* lsig  = (const float*)d_in[5];
    const float* atten = (const float*)d_in[6];
    const float* ln_sw = (const float*)d_in[7];
    const float* ln_sb = (const float*)d_in[8];
    const float* ln_mw = (const float*)d_in[9];
    const float* ln_mb = (const float*)d_in[10];
    const float* Wq    = (const float*)d_in[11];
    const float* Wk    = (const float*)d_in[12];
    const float* w_ih  = (const float*)d_in[13];
    const float* w_hh  = (const float*)d_in[14];
    const float* b_ih  = (const float*)d_in[15];
    const float* b_hh  = (const float*)d_in[16];
    const float* fc1w  = (const float*)d_in[17];
    const float* fc1b  = (const float*)d_in[18];
    const float* fc2w  = (const float*)d_in[19];
    const float* fc2b  = (const float*)d_in[20];

    float* out = (float*)d_out;
    char* ws = (char*)d_ws;
    size_t off = 0;
    auto alloc = [&](size_t nbytes) {
        void* p = ws + off;
        off += (nbytes + 255) & ~(size_t)255;
        return p;
    };
    float*          slotsA = (float*)alloc((size_t)E * HD * 4);
    float*          kbuf   = (float*)alloc((size_t)E * 64 * 4);
    float*          alpha  = (float*)alloc((size_t)E * 8 * 4);
    unsigned*       segmax = (unsigned*)alloc((size_t)Nn * 8 * 4);
    float*          segsum = (float*)alloc((size_t)Nn * 8 * 4);
    float*          vbuf   = (float*)alloc(512 * 4);
    unsigned short* B1img  = (unsigned short*)alloc(16384 * 2);
    unsigned short* B2img  = (unsigned short*)alloc(16384 * 2);
    unsigned short* wb     = (unsigned short*)alloc((size_t)1572864 * 2);
    unsigned short* u_g    = (unsigned short*)alloc((size_t)E * HD * 2);
    unsigned short* h_g    = (unsigned short*)alloc((size_t)E * HD * 2);

    const int GRU_LDS_BYTES = 4864 * 16;   // 76 KB
    const int MLP_LDS_BYTES = 36864 * 2;   // 72 KB
    hipFuncSetAttribute((const void*)gru_mfma,
                        hipFuncAttributeMaxDynamicSharedMemorySize, GRU_LDS_BYTES);
    hipFuncSetAttribute((const void*)mlp_mfma,
                        hipFuncAttributeMaxDynamicSharedMemorySize, MLP_LDS_BYTES);

    prep_v<<<1, 512, 0, stream>>>(atten, Wq, vbuf);
    prep_mlp<<<128, 256, 0, stream>>>(fc1w, fc2w, B1img, B2img);
    wprep<<<6144, 256, 0, stream>>>(w_ih, w_hh, wb);
    compute_k<<<4096, 256, 0, stream>>>(x, Wk, kbuf);
    init_slots<<<2048, 256, 0, stream>>>(nd, mu, lsig, slotsA, h_g);

    // iteration-0 alpha (later iterations: fused into mlp_mfma)
    seg_init<<<512, 256, 0, stream>>>(segmax, segsum);
    alpha_ln<<<E * 8 / 4, 256, 0, stream>>>(slotsA, vbuf, ln_sw, ln_sb, eidx, alpha, segmax);

    float* cur = slotsA;
    float* nxt = out;
    for (int it = 0; it < 3; ++it) {
        exp_sum<<<E * 8 / 256, 256, 0, stream>>>(eidx, segmax, alpha, segsum);
        prep_u<<<E / 256, 256, 0, stream>>>(kbuf, alpha, segsum, eidx, u_g);
        gru_mfma<<<16384, 256, GRU_LDS_BYTES, stream>>>(u_g, h_g, wb, b_ih, b_hh, nxt);
        if (it < 2)
            seg_init<<<512, 256, 0, stream>>>(segmax, segsum);
        mlp_mfma<<<32768, 256, MLP_LDS_BYTES, stream>>>(nxt, B1img, B2img, ln_mw, ln_mb,
                                                        fc1b, fc2b, h_g, (it < 2) ? 1 : 0,
                                                        ln_sw, ln_sb, vbuf, eidx, alpha, segmax);
        float* tmp = cur; cur = nxt; nxt = tmp;
    }
    (void)in_sizes; (void)n_in; (void)out_size; (void)ws_size;
}

// Round 9
// 5840.723 us; speedup vs baseline: 1.3619x; 1.1400x over previous
//
#include <hip/hip_runtime.h>
#include <math.h>

#define E 262144
#define Nn 16384
#define H 8
#define D 64
#define HD 512
#define HID 256

typedef float f32x4 __attribute__((ext_vector_type(4)));
typedef short bf16x8 __attribute__((ext_vector_type(8)));

__device__ __forceinline__ unsigned short f2bf(float f) {
    unsigned u = __float_as_uint(f);
    return (unsigned short)((u + 0x7fffu + ((u >> 16) & 1u)) >> 16);
}

__device__ __forceinline__ float bf2f(unsigned short u) {
    return __uint_as_float((unsigned)u << 16);
}

__device__ __forceinline__ void gl_lds16(const void* g, void* l) {
    __builtin_amdgcn_global_load_lds(
        (const __attribute__((address_space(1))) void*)g,
        (__attribute__((address_space(3))) void*)l, 16, 0, 0);
}

// v[h][j] = sum_d atten[h][d] * Wq[d][j]
__global__ void prep_v(const float* __restrict__ atten, const float* __restrict__ Wq,
                       float* __restrict__ v) {
    int t = threadIdx.x;            // 512 threads
    int h = t >> 6, j = t & 63;
    float a = 0.f;
    #pragma unroll 8
    for (int d = 0; d < 64; ++d) a += atten[h * 64 + d] * Wq[d * 64 + j];
    v[h * 64 + j] = a;
}

// MLP weight images (bf16, MFMA-frag layout, kg-XOR bank swizzle baked in)
__global__ void prep_mlp(const float* __restrict__ fc1w, const float* __restrict__ fc2w,
                         unsigned short* __restrict__ B1img, unsigned short* __restrict__ B2img) {
    int i = blockIdx.x * 256 + threadIdx.x;   // 32768 total
    if (i < 16384) {
        int j = i & 7, g = i >> 3;
        int cs = g & 255, kgkt = g >> 8;
        int kg = kgkt & 3, kt = kgkt >> 2;
        int c = cs ^ kg;
        int k = kt * 32 + kg * 8 + j;
        B1img[i] = f2bf(fc1w[c * 64 + k]);
    } else {
        int i2 = i - 16384;
        int j = i2 & 7, g = i2 >> 3;
        int ds = g & 63, kgkt = g >> 6;
        int kg = kgkt & 3, kt = kgkt >> 2;
        int dd = ds ^ kg;
        int c = kt * 32 + kg * 8 + j;
        B2img[i2] = f2bf(fc2w[dd * 256 + c]);
    }
}

// GRU weights bf16 image for BN=32:
// wb[cb(16)][t(16)][m(6)][kg(4)][cs(32)][j(8)] = w[(m%3)*512 + cb*32 + (cs^kg)][t*32+kg*8+j]
__global__ void wprep(const float* __restrict__ w_ih, const float* __restrict__ w_hh,
                      unsigned short* __restrict__ wb) {
    int o = blockIdx.x * 256 + threadIdx.x;   // 1,572,864 total
    int slice = o / 6144;
    int w = o - slice * 6144;
    int t = slice & 15, cb = slice >> 4;
    int j = w & 7;
    int cs = (w >> 3) & 31;
    int kgm = w >> 8;
    int kg = kgm & 3, m = kgm >> 2;
    const float* wm = (m < 3) ? w_ih : w_hh;
    int row = (m % 3) * 512 + cb * 32 + (cs ^ kg);
    int k = t * 32 + kg * 8 + j;
    wb[o] = f2bf(wm[(size_t)row * 512 + k]);
}

// k[e][d] = 0.125 * sum_j x[e][j] * Wk[d][j]
__global__ __launch_bounds__(256) void compute_k(const float* __restrict__ x,
                                                 const float* __restrict__ Wk,
                                                 float* __restrict__ kbuf) {
    __shared__ float sWk[64][130];
    int t = threadIdx.x;
    for (int i = t; i < 64 * 128; i += 256) sWk[i >> 7][i & 127] = Wk[i];
    __syncthreads();
    int lane = t & 63, w = t >> 6;
    for (int e = blockIdx.x * 4 + w; e < E; e += gridDim.x * 4) {
        const float* xr = x + (size_t)e * 128;
        float acc = 0.f;
        #pragma unroll 8
        for (int j = 0; j < 128; ++j) acc += xr[j] * sWk[lane][j];
        kbuf[(size_t)e * 64 + lane] = acc * 0.125f;
    }
}

__global__ void seg_init(unsigned* __restrict__ segmax, float* __restrict__ segsum) {
    int i = blockIdx.x * 256 + threadIdx.x;
    if (i < Nn * H) { segmax[i] = 0u; segsum[i] = 0.f; }
}

// slots = mu + exp(log_sigma)*norm_dist ; emit bf16 h_g image ; FUSED iteration-0 alpha
// (LN over each 64-row in 16-lane subgroup shuffles + v_h dot + leaky + segmax atomicMax)
__global__ void init_slots(const float* __restrict__ nd, const float* __restrict__ mu,
                           const float* __restrict__ lsig, float* __restrict__ out,
                           unsigned short* __restrict__ h_g,
                           const float* __restrict__ lnw, const float* __restrict__ lnb,
                           const float* __restrict__ vb, const int* __restrict__ eidx,
                           float* __restrict__ alpha, unsigned* __restrict__ segmax) {
    __shared__ float sMu[64], sSig[64];
    if (threadIdx.x < 64) {
        sMu[threadIdx.x]  = mu[threadIdx.x];
        sSig[threadIdx.x] = __expf(lsig[threadIdx.x]);
    }
    __syncthreads();
    size_t n4 = (size_t)E * HD / 4;
    size_t stride = (size_t)gridDim.x * blockDim.x;
    for (size_t i = (size_t)blockIdx.x * blockDim.x + threadIdx.x; i < n4; i += stride) {
        float4 v = ((const float4*)nd)[i];
        size_t flat = i * 4;
        int d0 = (int)(flat & 63);
        v.x = sMu[d0]     + sSig[d0]     * v.x;
        v.y = sMu[d0 + 1] + sSig[d0 + 1] * v.y;
        v.z = sMu[d0 + 2] + sSig[d0 + 2] * v.z;
        v.w = sMu[d0 + 3] + sSig[d0 + 3] * v.w;
        ((float4*)out)[i] = v;
        int e = (int)(flat >> 9);
        int k = (int)(flat & 511);
        int tt = k >> 5, kgg = (k >> 3) & 3, jo = k & 7;  // jo in {0,4}
        uint2 pk;
        pk.x = (unsigned)f2bf(v.x) | ((unsigned)f2bf(v.y) << 16);
        pk.y = (unsigned)f2bf(v.z) | ((unsigned)f2bf(v.w) << 16);
        *(uint2*)(h_g + ((size_t)(tt * 4 + kgg) * E + e) * 8 + jo) = pk;
        // ---- fused alpha: 16 consecutive lanes own one (e,h) row ----
        float s = v.x + v.y + v.z + v.w;
        s += __shfl_xor(s, 1, 64); s += __shfl_xor(s, 2, 64);
        s += __shfl_xor(s, 4, 64); s += __shfl_xor(s, 8, 64);
        float mean = s * (1.f / 64.f);
        float sq = (v.x - mean) * (v.x - mean) + (v.y - mean) * (v.y - mean)
                 + (v.z - mean) * (v.z - mean) + (v.w - mean) * (v.w - mean);
        sq += __shfl_xor(sq, 1, 64); sq += __shfl_xor(sq, 2, 64);
        sq += __shfl_xor(sq, 4, 64); sq += __shfl_xor(sq, 8, 64);
        float rs = rsqrtf(sq * (1.f / 64.f) + 1e-5f);
        size_t p = flat >> 6;           // row index (e*8+h)
        int h = (int)(p & 7);
        float dp = ((v.x - mean) * rs * lnw[d0]     + lnb[d0])     * vb[h * 64 + d0]
                 + ((v.y - mean) * rs * lnw[d0 + 1] + lnb[d0 + 1]) * vb[h * 64 + d0 + 1]
                 + ((v.z - mean) * rs * lnw[d0 + 2] + lnb[d0 + 2]) * vb[h * 64 + d0 + 2]
                 + ((v.w - mean) * rs * lnw[d0 + 3] + lnb[d0 + 3]) * vb[h * 64 + d0 + 3];
        dp += __shfl_xor(dp, 1, 64); dp += __shfl_xor(dp, 2, 64);
        dp += __shfl_xor(dp, 4, 64); dp += __shfl_xor(dp, 8, 64);
        if ((threadIdx.x & 15) == 0) {
            float a = dp * 0.125f;
            a = a >= 0.f ? a : 0.2f * a;
            alpha[p] = a;
            unsigned b = __float_as_uint(a);
            unsigned enc = (b & 0x80000000u) ? ~b : (b | 0x80000000u);
            atomicMax(&segmax[eidx[e] * 8 + h], enc);
        }
    }
}

__global__ void exp_sum(const int* __restrict__ eidx, const unsigned* __restrict__ segmax,
                        float* __restrict__ alpha, float* __restrict__ segsum) {
    size_t p = (size_t)blockIdx.x * 256 + threadIdx.x;
    int e = (int)(p >> 3), h = (int)(p & 7);
    int id = eidx[e];
    unsigned u = segmax[id * 8 + h];
    float m = __uint_as_float((u & 0x80000000u) ? (u & 0x7fffffffu) : ~u);
    float val = __expf(alpha[p] - m);
    alpha[p] = val;
    atomicAdd(&segsum[id * 8 + h], val);
}

// normalize alpha + build u_g = bf16((k*alpha)) in [t][kg][E][8] layout. thread per edge.
__global__ __launch_bounds__(256) void prep_u(const float* __restrict__ kbuf,
                                              const float* __restrict__ alpha,
                                              const float* __restrict__ segsum,
                                              const int* __restrict__ eidx,
                                              unsigned short* __restrict__ u_g) {
    int e = blockIdx.x * 256 + threadIdx.x;
    int id = eidx[e];
    float a[8];
    #pragma unroll
    for (int h = 0; h < 8; ++h)
        a[h] = alpha[(size_t)e * 8 + h] / (segsum[id * 8 + h] + 1e-16f);
    float4 kv[16];
    const float4* kr = (const float4*)(kbuf + (size_t)e * 64);
    #pragma unroll
    for (int q = 0; q < 16; ++q) kv[q] = kr[q];
    const float* kf = (const float*)kv;
    #pragma unroll
    for (int tt = 0; tt < 16; ++tt) {
        float ah = a[tt >> 1];
        #pragma unroll
        for (int kg = 0; kg < 4; ++kg) {
            int dbase = (tt & 1) * 32 + kg * 8;
            bf16x8 v;
            #pragma unroll
            for (int j = 0; j < 8; ++j) v[j] = (short)f2bf(kf[dbase + j] * ah);
            *(bf16x8*)(u_g + ((size_t)(tt * 4 + kg) * E + e) * 8) = v;
        }
    }
}

// ---------------- MFMA GRU : BM=256 x BN=32, BK=32, dbuf-A + counted vmcnt ----------------
__global__ __launch_bounds__(256, 2) void gru_mfma(
    const unsigned short* __restrict__ u_g, const unsigned short* __restrict__ h_g,
    const unsigned short* __restrict__ wb,
    const float* __restrict__ b_ih, const float* __restrict__ b_hh,
    float* __restrict__ nxt) {

    extern __shared__ unsigned short lds[];

    int bid = blockIdx.x;
    int lbid = (bid & 7) * 2048 + (bid >> 3);   // XCD-contiguous chunks (16384 % 8 == 0)
    int eb = lbid >> 4, cb = lbid & 15;
    int e0 = eb * 256;
    int t = threadIdx.x;
    int lane = t & 63, wid = t >> 6;
    int li = lane & 15, kg = lane >> 4;
    int EB = wid * 64;

    const unsigned short* wsl = wb + (size_t)(cb * 16) * 6144;

    f32x4 acc[4][4][2] = {};   // [plane][m][f]

    auto stage_a = [&](int ts, int p) {
        #pragma unroll
        for (int c = 0; c < 8; ++c) {
            int i = c * 256 + t;
            unsigned short* lp = lds + (size_t)(p * 2048 + c * 256 + (t & ~63)) * 8;
            const unsigned short* gp;
            if (c < 4) {
                int kgg = i >> 8, el = i & 255;
                gp = u_g + ((size_t)(ts * 4 + kgg) * E + (e0 + el)) * 8;
            } else {
                int i2 = i - 1024; int kgg = i2 >> 8, el = i2 & 255;
                gp = h_g + ((size_t)(ts * 4 + kgg) * E + (e0 + el)) * 8;
            }
            gl_lds16(gp, lp);
        }
    };
    auto stage_w = [&](int ts) {
        #pragma unroll
        for (int c = 0; c < 3; ++c) {
            int i = c * 256 + t;
            unsigned short* lp = lds + (size_t)(4096 + c * 256 + (t & ~63)) * 8;
            const unsigned short* gp = wsl + ((size_t)ts * 768 + i) * 8;
            gl_lds16(gp, lp);
        }
    };
    auto compute = [&](int p) {
        bf16x8 au[4], ah[4];
        #pragma unroll
        for (int m = 0; m < 4; ++m) {
            int ea = p * 2048 + kg * 256 + EB + m * 16 + li;
            au[m] = *(bf16x8*)(lds + (size_t)ea * 8);
            ah[m] = *(bf16x8*)(lds + (size_t)(1024 + ea) * 8);
        }
        const unsigned short* W = lds + (size_t)4096 * 8;
        #pragma unroll
        for (int f = 0; f < 2; ++f) {
            int cs = (f * 16 + li) ^ kg;
            bf16x8 bir = *(bf16x8*)(W + ((size_t)(0 * 4 + kg) * 32 + cs) * 8);
            bf16x8 biz = *(bf16x8*)(W + ((size_t)(1 * 4 + kg) * 32 + cs) * 8);
            bf16x8 bin = *(bf16x8*)(W + ((size_t)(2 * 4 + kg) * 32 + cs) * 8);
            bf16x8 bhr = *(bf16x8*)(W + ((size_t)(3 * 4 + kg) * 32 + cs) * 8);
            bf16x8 bhz = *(bf16x8*)(W + ((size_t)(4 * 4 + kg) * 32 + cs) * 8);
            bf16x8 bhn = *(bf16x8*)(W + ((size_t)(5 * 4 + kg) * 32 + cs) * 8);
            #pragma unroll
            for (int m = 0; m < 4; ++m) {
                acc[0][m][f] = __builtin_amdgcn_mfma_f32_16x16x32_bf16(au[m], bir, acc[0][m][f], 0, 0, 0);
                acc[0][m][f] = __builtin_amdgcn_mfma_f32_16x16x32_bf16(ah[m], bhr, acc[0][m][f], 0, 0, 0);
                acc[1][m][f] = __builtin_amdgcn_mfma_f32_16x16x32_bf16(au[m], biz, acc[1][m][f], 0, 0, 0);
                acc[1][m][f] = __builtin_amdgcn_mfma_f32_16x16x32_bf16(ah[m], bhz, acc[1][m][f], 0, 0, 0);
                acc[2][m][f] = __builtin_amdgcn_mfma_f32_16x16x32_bf16(au[m], bin, acc[2][m][f], 0, 0, 0);
                acc[3][m][f] = __builtin_amdgcn_mfma_f32_16x16x32_bf16(ah[m], bhn, acc[3][m][f], 0, 0, 0);
            }
        }
    };

    // prologue: tile 0 in flight (11 ops/thread)
    stage_a(0, 0);
    stage_w(0);

    for (int ts = 0; ts < 15; ++ts) {
        int p = ts & 1;
        stage_a(ts + 1, p ^ 1);                     // +8 in flight
        asm volatile("s_waitcnt vmcnt(8)" ::: "memory");
        __builtin_amdgcn_s_barrier();
        compute(p);
        asm volatile("" ::: "memory");
        __builtin_amdgcn_s_barrier();               // all waves done with W(ts) + bufA[p]
        stage_w(ts + 1);                            // +3 in flight
    }
    asm volatile("s_waitcnt vmcnt(0)" ::: "memory");
    __builtin_amdgcn_s_barrier();
    compute(1);                                     // ts = 15

    // epilogue: gates f32, hprev from h_g (bf16)
    #pragma unroll
    for (int f = 0; f < 2; ++f) {
        int c = cb * 32 + f * 16 + li;
        float br = b_ih[c] + b_hh[c];
        float bz = b_ih[c + 512] + b_hh[c + 512];
        float bi = b_ih[c + 1024];
        float bh = b_hh[c + 1024];
        size_t hb = (size_t)(c >> 3) * E * 8 + (c & 7);
        #pragma unroll
        for (int m = 0; m < 4; ++m) {
            #pragma unroll
            for (int q = 0; q < 4; ++q) {
                size_t ge = (size_t)(e0 + EB + m * 16 + kg * 4 + q);
                float r = 1.f / (1.f + __expf(-(acc[0][m][f][q] + br)));
                float z = 1.f / (1.f + __expf(-(acc[1][m][f][q] + bz)));
                float n = tanhf(acc[2][m][f][q] + bi + r * (acc[3][m][f][q] + bh));
                float hp = bf2f(h_g[hb + ge * 8]);
                nxt[ge * 512 + c] = (1.f - z) * n + z * hp;
            }
        }
    }
}

// ---------------- Persistent-weight MFMA MLP ----------------
// 256 blocks x 512 threads (2 groups of 4 waves). B1+B2 staged ONCE (64 KB LDS).
// Per block: 64 tile-pairs, each group one 64-row tile/iter, next-tile rows prefetched.
// LDS ushorts: B1 [0,16384) | B2 [16384,32768) | A1 [32768 + grp*4096) | Y1 [40960 + grp*16384)
__global__ __launch_bounds__(512, 1) void mlp_fused(
    float* __restrict__ slots,
    const unsigned short* __restrict__ B1img, const unsigned short* __restrict__ B2img,
    const float* __restrict__ lnw, const float* __restrict__ lnb,
    const float* __restrict__ fc1b, const float* __restrict__ fc2b,
    unsigned short* __restrict__ h_g, int write_hg,
    const float* __restrict__ lnsw, const float* __restrict__ lnsb,
    const float* __restrict__ vb, const int* __restrict__ eidx,
    float* __restrict__ alpha_out, unsigned* __restrict__ segmax) {

    extern __shared__ unsigned short mlds[];
    unsigned short* B1 = mlds;
    unsigned short* B2 = mlds + 16384;

    int t = threadIdx.x;
    int lane = t & 63;
    int li = lane & 15, kg = lane >> 4;
    int wid = t >> 6;
    int grp = wid >> 2, wl = wid & 3;
    int tt = t & 255;                       // thread id within group
    unsigned short* A1 = mlds + 32768 + grp * 4096;
    unsigned short* Y1 = mlds + 40960 + grp * 16384;

    // ---- stage all weights once (4096 x 16B entries) ----
    #pragma unroll
    for (int c = 0; c < 8; ++c) {
        int i = c * 512 + t;
        const unsigned short* gp = (i < 2048) ? B1img + (size_t)i * 8
                                              : B2img + (size_t)(i - 2048) * 8;
        gl_lds16(gp, mlds + (size_t)(c * 512 + (t & ~63)) * 8);
    }

    int base = blockIdx.x * 128;            // 128 tiles per block
    int r = tt >> 2, c0 = (tt & 3) * 16;    // phase-0 role: row r, cols [c0,c0+16)

    // prologue: load rows of first tile
    float4 xr0, xr1, xr2, xr3;
    {
        const float* rowp = slots + ((size_t)(base + grp) * 64 + r) * 64 + c0;
        xr0 = ((const float4*)rowp)[0]; xr1 = ((const float4*)rowp)[1];
        xr2 = ((const float4*)rowp)[2]; xr3 = ((const float4*)rowp)[3];
    }
    asm volatile("s_waitcnt vmcnt(0)" ::: "memory");   // weights + first rows ready
    __syncthreads();

    for (int j = 0; j < 64; ++j) {
        int tile = base + 2 * j + grp;
        size_t p0 = (size_t)tile * 64;

        // ---- phase 0: LN from regs -> A1 frag tile ----
        {
            float s = xr0.x + xr0.y + xr0.z + xr0.w + xr1.x + xr1.y + xr1.z + xr1.w
                    + xr2.x + xr2.y + xr2.z + xr2.w + xr3.x + xr3.y + xr3.z + xr3.w;
            s += __shfl_xor(s, 1, 64); s += __shfl_xor(s, 2, 64);
            float m = s * (1.f / 64.f);
            float xv[16] = {xr0.x, xr0.y, xr0.z, xr0.w, xr1.x, xr1.y, xr1.z, xr1.w,
                            xr2.x, xr2.y, xr2.z, xr2.w, xr3.x, xr3.y, xr3.z, xr3.w};
            float sq = 0.f;
            #pragma unroll
            for (int i = 0; i < 16; ++i) { float dd = xv[i] - m; sq += dd * dd; }
            sq += __shfl_xor(sq, 1, 64); sq += __shfl_xor(sq, 2, 64);
            float rs = rsqrtf(sq * (1.f / 64.f) + 1e-5f);
            unsigned short u[16];
            #pragma unroll
            for (int i = 0; i < 16; ++i)
                u[i] = f2bf((xv[i] - m) * rs * lnw[c0 + i] + lnb[c0 + i]);
            int g0 = (tt & 3) * 2, g1 = g0 + 1;
            *(bf16x8*)(A1 + g0 * 512 + ((r * 8) ^ ((g0 & 3) * 8))) = *(bf16x8*)&u[0];
            *(bf16x8*)(A1 + g1 * 512 + ((r * 8) ^ ((g1 & 3) * 8))) = *(bf16x8*)&u[8];
        }
        // prefetch next tile's rows (latency hides under fc1+fc2)
        float4 xn0, xn1, xn2, xn3;
        if (j + 1 < 64) {
            const float* rowp = slots + ((size_t)(base + 2 * (j + 1) + grp) * 64 + r) * 64 + c0;
            xn0 = ((const float4*)rowp)[0]; xn1 = ((const float4*)rowp)[1];
            xn2 = ((const float4*)rowp)[2]; xn3 = ((const float4*)rowp)[3];
        }
        __syncthreads();                     // A1 visible; prev Y1 reads done

        // ---- fc1 (swapped operands) ----
        f32x4 acc1[4][4] = {};
        #pragma unroll
        for (int kt = 0; kt < 2; ++kt) {
            bf16x8 bfrag[4];
            #pragma unroll
            for (int rt = 0; rt < 4; ++rt)
                bfrag[rt] = *(bf16x8*)(A1 + (kt * 4 + kg) * 512 + (((rt * 16 + li) * 8) ^ (kg * 8)));
            #pragma unroll
            for (int ct = 0; ct < 4; ++ct) {
                bf16x8 af = *(bf16x8*)(B1 + kt * 8192 + kg * 2048 + (((wl * 64 + ct * 16 + li) ^ kg) * 8));
                #pragma unroll
                for (int rt = 0; rt < 4; ++rt)
                    acc1[ct][rt] = __builtin_amdgcn_mfma_f32_16x16x32_bf16(af, bfrag[rt], acc1[ct][rt], 0, 0, 0);
            }
        }
        // ---- bias + relu -> Y1 ----
        #pragma unroll
        for (int ct = 0; ct < 4; ++ct) {
            int cc = wl * 64 + ct * 16 + kg * 4;
            float4 b1 = *(const float4*)(fc1b + cc);
            int g = cc >> 3;
            #pragma unroll
            for (int rt = 0; rt < 4; ++rt) {
                f32x4 vv = acc1[ct][rt];
                float y0 = fmaxf(vv[0] + b1.x, 0.f), y1v = fmaxf(vv[1] + b1.y, 0.f);
                float y2 = fmaxf(vv[2] + b1.z, 0.f), y3 = fmaxf(vv[3] + b1.w, 0.f);
                unsigned lo = (unsigned)f2bf(y0) | ((unsigned)f2bf(y1v) << 16);
                unsigned hi = (unsigned)f2bf(y2) | ((unsigned)f2bf(y3) << 16);
                int rr = rt * 16 + li;
                int off = g * 512 + ((rr * 8) ^ ((g & 3) * 8)) + (cc & 7);
                uint2 pk; pk.x = lo; pk.y = hi;
                *(uint2*)(Y1 + off) = pk;
            }
        }
        __syncthreads();                     // Y1 visible

        // ---- fc2 ----
        f32x4 acc2[4] = {};
        #pragma unroll
        for (int hc = 0; hc < 2; ++hc) {
            #pragma unroll
            for (int ktl = 0; ktl < 4; ++ktl) {
                int ktg = hc * 4 + ktl;
                bf16x8 af = *(bf16x8*)(Y1 + (ktg * 4 + kg) * 512 + (((wl * 16 + li) * 8) ^ (kg * 8)));
                #pragma unroll
                for (int nt = 0; nt < 4; ++nt) {
                    bf16x8 bf = *(bf16x8*)(B2 + hc * 8192 + (ktl * 4 + kg) * 512 + (((nt * 16 + li) ^ kg) * 8));
                    acc2[nt] = __builtin_amdgcn_mfma_f32_16x16x32_bf16(af, bf, acc2[nt], 0, 0, 0);
                }
            }
        }

        // ---- epilogue: residual add; stash bf16 into A1; alpha + h_g if needed ----
        float vals[4][4];
        #pragma unroll
        for (int nt = 0; nt < 4; ++nt) {
            int dd = nt * 16 + li;
            float b2 = fc2b[dd];
            #pragma unroll
            for (int q = 0; q < 4; ++q) {
                int rr = wl * 16 + kg * 4 + q;
                size_t gp = (p0 + rr) * 64 + dd;
                float val = slots[gp] + acc2[nt][q] + b2;
                slots[gp] = val;
                A1[rr * 64 + dd] = f2bf(val);
                vals[nt][q] = val;
            }
        }
        if (write_hg) {
            #pragma unroll
            for (int q = 0; q < 4; ++q) {
                int rr = wl * 16 + kg * 4 + q;
                float s = vals[0][q] + vals[1][q] + vals[2][q] + vals[3][q];
                s += __shfl_xor(s, 1, 64); s += __shfl_xor(s, 2, 64);
                s += __shfl_xor(s, 4, 64); s += __shfl_xor(s, 8, 64);
                float mean = s * (1.f / 64.f);
                float sq = 0.f;
                #pragma unroll
                for (int nt = 0; nt < 4; ++nt) { float d = vals[nt][q] - mean; sq += d * d; }
                sq += __shfl_xor(sq, 1, 64); sq += __shfl_xor(sq, 2, 64);
                sq += __shfl_xor(sq, 4, 64); sq += __shfl_xor(sq, 8, 64);
                float rs = rsqrtf(sq * (1.f / 64.f) + 1e-5f);
                int h = rr & 7;
                float dp = 0.f;
                #pragma unroll
                for (int nt = 0; nt < 4; ++nt) {
                    int dd = nt * 16 + li;
                    float ln = (vals[nt][q] - mean) * rs * lnsw[dd] + lnsb[dd];
                    dp += ln * vb[h * 64 + dd];
                }
                dp += __shfl_xor(dp, 1, 64); dp += __shfl_xor(dp, 2, 64);
                dp += __shfl_xor(dp, 4, 64); dp += __shfl_xor(dp, 8, 64);
                if (li == 0) {
                    float a = dp * 0.125f;
                    a = a >= 0.f ? a : 0.2f * a;
                    size_t p = p0 + rr;
                    alpha_out[p] = a;
                    int e = (int)(p >> 3);
                    unsigned b = __float_as_uint(a);
                    unsigned enc = (b & 0x80000000u) ? ~b : (b | 0x80000000u);
                    atomicMax(&segmax[eidx[e] * 8 + h], enc);
                }
            }
            __syncthreads();                 // A1 stash visible within group
            #pragma unroll
            for (int c2 = 0; c2 < 2; ++c2) {
                int n = c2 * 256 + tt;       // (h*8+g)*8 + eloc
                int eloc = n & 7;
                int hg8 = n >> 3;
                int hh = hg8 >> 3, g = hg8 & 7;
                int rr = eloc * 8 + hh;
                bf16x8 v = *(bf16x8*)(A1 + rr * 64 + g * 8);
                int k = hh * 64 + g * 8;
                int ts = k >> 5, kgg = (k >> 3) & 3;
                size_t e = (size_t)tile * 8 + eloc;
                *(bf16x8*)(h_g + ((size_t)(ts * 4 + kgg) * E + e) * 8) = v;
            }
        }
        __syncthreads();                     // A1/Y1 free for next iteration
        xr0 = xn0; xr1 = xn1; xr2 = xn2; xr3 = xn3;
    }
}

extern "C" void kernel_launch(void* const* d_in, const int* in_sizes, int n_in,
                              void* d_out, int out_size, void* d_ws, size_t ws_size,
                              hipStream_t stream) {
    const float* x     = (const float*)d_in[0];
    const int*   eidx  = (const int*)d_in[1];
    const float* nd    = (const float*)d_in[3];
    const float* mu    = (const float*)d_in[4];
    const float* lsig  = (const float*)d_in[5];
    const float* atten = (const float*)d_in[6];
    const float* ln_sw = (const float*)d_in[7];
    const float* ln_sb = (const float*)d_in[8];
    const float* ln_mw = (const float*)d_in[9];
    const float* ln_mb = (const float*)d_in[10];
    const float* Wq    = (const float*)d_in[11];
    const float* Wk    = (const float*)d_in[12];
    const float* w_ih  = (const float*)d_in[13];
    const float* w_hh  = (const float*)d_in[14];
    const float* b_ih  = (const float*)d_in[15];
    const float* b_hh  = (const float*)d_in[16];
    const float* fc1w  = (const float*)d_in[17];
    const float* fc1b  = (const float*)d_in[18];
    const float* fc2w  = (const float*)d_in[19];
    const float* fc2b  = (const float*)d_in[20];

    float* out = (float*)d_out;
    char* ws = (char*)d_ws;
    size_t off = 0;
    auto alloc = [&](size_t nbytes) {
        void* p = ws + off;
        off += (nbytes + 255) & ~(size_t)255;
        return p;
    };
    float*          slotsA = (float*)alloc((size_t)E * HD * 4);
    float*          kbuf   = (float*)alloc((size_t)E * 64 * 4);
    float*          alpha  = (float*)alloc((size_t)E * 8 * 4);
    unsigned*       segmax = (unsigned*)alloc((size_t)Nn * 8 * 4);
    float*          segsum = (float*)alloc((size_t)Nn * 8 * 4);
    float*          vbuf   = (float*)alloc(512 * 4);
    unsigned short* B1img  = (unsigned short*)alloc(16384 * 2);
    unsigned short* B2img  = (unsigned short*)alloc(16384 * 2);
    unsigned short* wb     = (unsigned short*)alloc((size_t)1572864 * 2);
    unsigned short* u_g    = (unsigned short*)alloc((size_t)E * HD * 2);
    unsigned short* h_g    = (unsigned short*)alloc((size_t)E * HD * 2);

    const int GRU_LDS_BYTES = 4864 * 16;    // 76 KB
    const int MLP_LDS_BYTES = 73728 * 2;    // 144 KB
    hipFuncSetAttribute((const void*)gru_mfma,
                        hipFuncAttributeMaxDynamicSharedMemorySize, GRU_LDS_BYTES);
    hipFuncSetAttribute((const void*)mlp_fused,
                        hipFuncAttributeMaxDynamicSharedMemorySize, MLP_LDS_BYTES);

    prep_v<<<1, 512, 0, stream>>>(atten, Wq, vbuf);
    prep_mlp<<<128, 256, 0, stream>>>(fc1w, fc2w, B1img, B2img);
    wprep<<<6144, 256, 0, stream>>>(w_ih, w_hh, wb);
    compute_k<<<4096, 256, 0, stream>>>(x, Wk, kbuf);
    seg_init<<<512, 256, 0, stream>>>(segmax, segsum);
    init_slots<<<2048, 256, 0, stream>>>(nd, mu, lsig, slotsA, h_g,
                                         ln_sw, ln_sb, vbuf, eidx, alpha, segmax);

    float* cur = slotsA;
    float* nxt = out;
    for (int it = 0; it < 3; ++it) {
        exp_sum<<<E * 8 / 256, 256, 0, stream>>>(eidx, segmax, alpha, segsum);
        prep_u<<<E / 256, 256, 0, stream>>>(kbuf, alpha, segsum, eidx, u_g);
        gru_mfma<<<16384, 256, GRU_LDS_BYTES, stream>>>(u_g, h_g, wb, b_ih, b_hh, nxt);
        if (it < 2)
            seg_init<<<512, 256, 0, stream>>>(segmax, segsum);
        mlp_fused<<<256, 512, MLP_LDS_BYTES, stream>>>(nxt, B1img, B2img, ln_mw, ln_mb,
                                                       fc1b, fc2b, h_g, (it < 2) ? 1 : 0,
                                                       ln_sw, ln_sb, vbuf, eidx, alpha, segmax);
        float* tmp = cur; cur = nxt; nxt = tmp;
    }
    (void)in_sizes; (void)n_in; (void)out_size; (void)ws_size;
}

// Round 11
// 5297.576 us; speedup vs baseline: 1.5015x; 1.1025x over previous
//
#include <hip/hip_runtime.h>
#include <math.h>

#define E 262144
#define Nn 16384
#define H 8
#define D 64
#define HD 512
#define HID 256

typedef float f32x4 __attribute__((ext_vector_type(4)));
typedef short bf16x8 __attribute__((ext_vector_type(8)));

__device__ __forceinline__ unsigned short f2bf(float f) {
    unsigned u = __float_as_uint(f);
    return (unsigned short)((u + 0x7fffu + ((u >> 16) & 1u)) >> 16);
}

__device__ __forceinline__ float bf2f(unsigned short u) {
    return __uint_as_float((unsigned)u << 16);
}

__device__ __forceinline__ void gl_lds16(const void* g, void* l) {
    __builtin_amdgcn_global_load_lds(
        (const __attribute__((address_space(1))) void*)g,
        (__attribute__((address_space(3))) void*)l, 16, 0, 0);
}

// v[h][j] = sum_d atten[h][d] * Wq[d][j]
__global__ void prep_v(const float* __restrict__ atten, const float* __restrict__ Wq,
                       float* __restrict__ v) {
    int t = threadIdx.x;            // 512 threads
    int h = t >> 6, j = t & 63;
    float a = 0.f;
    #pragma unroll 8
    for (int d = 0; d < 64; ++d) a += atten[h * 64 + d] * Wq[d * 64 + j];
    v[h * 64 + j] = a;
}

// MLP weight images (bf16, MFMA-frag layout, kg-XOR bank swizzle baked in)
__global__ void prep_mlp(const float* __restrict__ fc1w, const float* __restrict__ fc2w,
                         unsigned short* __restrict__ B1img, unsigned short* __restrict__ B2img) {
    int i = blockIdx.x * 256 + threadIdx.x;   // 32768 total
    if (i < 16384) {
        int j = i & 7, g = i >> 3;
        int cs = g & 255, kgkt = g >> 8;
        int kg = kgkt & 3, kt = kgkt >> 2;
        int c = cs ^ kg;
        int k = kt * 32 + kg * 8 + j;
        B1img[i] = f2bf(fc1w[c * 64 + k]);
    } else {
        int i2 = i - 16384;
        int j = i2 & 7, g = i2 >> 3;
        int ds = g & 63, kgkt = g >> 6;
        int kg = kgkt & 3, kt = kgkt >> 2;
        int dd = ds ^ kg;
        int c = kt * 32 + kg * 8 + j;
        B2img[i2] = f2bf(fc2w[dd * 256 + c]);
    }
}

// GRU weights bf16 image for BN=32:
// wb[cb(16)][t(16)][m(6)][kg(4)][cs(32)][j(8)] = w[(m%3)*512 + cb*32 + (cs^kg)][t*32+kg*8+j]
__global__ void wprep(const float* __restrict__ w_ih, const float* __restrict__ w_hh,
                      unsigned short* __restrict__ wb) {
    int o = blockIdx.x * 256 + threadIdx.x;   // 1,572,864 total
    int slice = o / 6144;
    int w = o - slice * 6144;
    int t = slice & 15, cb = slice >> 4;
    int j = w & 7;
    int cs = (w >> 3) & 31;
    int kgm = w >> 8;
    int kg = kgm & 3, m = kgm >> 2;
    const float* wm = (m < 3) ? w_ih : w_hh;
    int row = (m % 3) * 512 + cb * 32 + (cs ^ kg);
    int k = t * 32 + kg * 8 + j;
    wb[o] = f2bf(wm[(size_t)row * 512 + k]);
}

// k[e][d] = 0.125 * sum_j x[e][j] * Wk[d][j]
__global__ __launch_bounds__(256) void compute_k(const float* __restrict__ x,
                                                 const float* __restrict__ Wk,
                                                 float* __restrict__ kbuf) {
    __shared__ float sWk[64][130];
    int t = threadIdx.x;
    for (int i = t; i < 64 * 128; i += 256) sWk[i >> 7][i & 127] = Wk[i];
    __syncthreads();
    int lane = t & 63, w = t >> 6;
    for (int e = blockIdx.x * 4 + w; e < E; e += gridDim.x * 4) {
        const float* xr = x + (size_t)e * 128;
        float acc = 0.f;
        #pragma unroll 8
        for (int j = 0; j < 128; ++j) acc += xr[j] * sWk[lane][j];
        kbuf[(size_t)e * 64 + lane] = acc * 0.125f;
    }
}

__global__ void seg_init(unsigned* __restrict__ segmax, float* __restrict__ segsum) {
    int i = blockIdx.x * 256 + threadIdx.x;
    if (i < Nn * H) { segmax[i] = 0u; segsum[i] = 0.f; }
}

// slots = mu + exp(log_sigma)*norm_dist ; emit bf16 h_g image ; FUSED iteration-0 alpha
__global__ void init_slots(const float* __restrict__ nd, const float* __restrict__ mu,
                           const float* __restrict__ lsig, float* __restrict__ out,
                           unsigned short* __restrict__ h_g,
                           const float* __restrict__ lnw, const float* __restrict__ lnb,
                           const float* __restrict__ vb, const int* __restrict__ eidx,
                           float* __restrict__ alpha, unsigned* __restrict__ segmax) {
    __shared__ float sMu[64], sSig[64];
    if (threadIdx.x < 64) {
        sMu[threadIdx.x]  = mu[threadIdx.x];
        sSig[threadIdx.x] = __expf(lsig[threadIdx.x]);
    }
    __syncthreads();
    size_t n4 = (size_t)E * HD / 4;
    size_t stride = (size_t)gridDim.x * blockDim.x;
    for (size_t i = (size_t)blockIdx.x * blockDim.x + threadIdx.x; i < n4; i += stride) {
        float4 v = ((const float4*)nd)[i];
        size_t flat = i * 4;
        int d0 = (int)(flat & 63);
        v.x = sMu[d0]     + sSig[d0]     * v.x;
        v.y = sMu[d0 + 1] + sSig[d0 + 1] * v.y;
        v.z = sMu[d0 + 2] + sSig[d0 + 2] * v.z;
        v.w = sMu[d0 + 3] + sSig[d0 + 3] * v.w;
        ((float4*)out)[i] = v;
        int e = (int)(flat >> 9);
        int k = (int)(flat & 511);
        int tt = k >> 5, kgg = (k >> 3) & 3, jo = k & 7;  // jo in {0,4}
        uint2 pk;
        pk.x = (unsigned)f2bf(v.x) | ((unsigned)f2bf(v.y) << 16);
        pk.y = (unsigned)f2bf(v.z) | ((unsigned)f2bf(v.w) << 16);
        *(uint2*)(h_g + ((size_t)(tt * 4 + kgg) * E + e) * 8 + jo) = pk;
        // ---- fused alpha: 16 consecutive lanes own one (e,h) row ----
        float s = v.x + v.y + v.z + v.w;
        s += __shfl_xor(s, 1, 64); s += __shfl_xor(s, 2, 64);
        s += __shfl_xor(s, 4, 64); s += __shfl_xor(s, 8, 64);
        float mean = s * (1.f / 64.f);
        float sq = (v.x - mean) * (v.x - mean) + (v.y - mean) * (v.y - mean)
                 + (v.z - mean) * (v.z - mean) + (v.w - mean) * (v.w - mean);
        sq += __shfl_xor(sq, 1, 64); sq += __shfl_xor(sq, 2, 64);
        sq += __shfl_xor(sq, 4, 64); sq += __shfl_xor(sq, 8, 64);
        float rs = rsqrtf(sq * (1.f / 64.f) + 1e-5f);
        size_t p = flat >> 6;           // row index (e*8+h)
        int h = (int)(p & 7);
        float dp = ((v.x - mean) * rs * lnw[d0]     + lnb[d0])     * vb[h * 64 + d0]
                 + ((v.y - mean) * rs * lnw[d0 + 1] + lnb[d0 + 1]) * vb[h * 64 + d0 + 1]
                 + ((v.z - mean) * rs * lnw[d0 + 2] + lnb[d0 + 2]) * vb[h * 64 + d0 + 2]
                 + ((v.w - mean) * rs * lnw[d0 + 3] + lnb[d0 + 3]) * vb[h * 64 + d0 + 3];
        dp += __shfl_xor(dp, 1, 64); dp += __shfl_xor(dp, 2, 64);
        dp += __shfl_xor(dp, 4, 64); dp += __shfl_xor(dp, 8, 64);
        if ((threadIdx.x & 15) == 0) {
            float a = dp * 0.125f;
            a = a >= 0.f ? a : 0.2f * a;
            alpha[p] = a;
            unsigned b = __float_as_uint(a);
            unsigned enc = (b & 0x80000000u) ? ~b : (b | 0x80000000u);
            atomicMax(&segmax[eidx[e] * 8 + h], enc);
        }
    }
}

__global__ void exp_sum(const int* __restrict__ eidx, const unsigned* __restrict__ segmax,
                        float* __restrict__ alpha, float* __restrict__ segsum) {
    size_t p = (size_t)blockIdx.x * 256 + threadIdx.x;
    int e = (int)(p >> 3), h = (int)(p & 7);
    int id = eidx[e];
    unsigned u = segmax[id * 8 + h];
    float m = __uint_as_float((u & 0x80000000u) ? (u & 0x7fffffffu) : ~u);
    float val = __expf(alpha[p] - m);
    alpha[p] = val;
    atomicAdd(&segsum[id * 8 + h], val);
}

// normalize alpha + build u_g = bf16((k*alpha)) in [t][kg][E][8] layout. thread per edge.
__global__ __launch_bounds__(256) void prep_u(const float* __restrict__ kbuf,
                                              const float* __restrict__ alpha,
                                              const float* __restrict__ segsum,
                                              const int* __restrict__ eidx,
                                              unsigned short* __restrict__ u_g) {
    int e = blockIdx.x * 256 + threadIdx.x;
    int id = eidx[e];
    float a[8];
    #pragma unroll
    for (int h = 0; h < 8; ++h)
        a[h] = alpha[(size_t)e * 8 + h] / (segsum[id * 8 + h] + 1e-16f);
    float4 kv[16];
    const float4* kr = (const float4*)(kbuf + (size_t)e * 64);
    #pragma unroll
    for (int q = 0; q < 16; ++q) kv[q] = kr[q];
    const float* kf = (const float*)kv;
    #pragma unroll
    for (int tt = 0; tt < 16; ++tt) {
        float ah = a[tt >> 1];
        #pragma unroll
        for (int kg = 0; kg < 4; ++kg) {
            int dbase = (tt & 1) * 32 + kg * 8;
            bf16x8 v;
            #pragma unroll
            for (int j = 0; j < 8; ++j) v[j] = (short)f2bf(kf[dbase + j] * ah);
            *(bf16x8*)(u_g + ((size_t)(tt * 4 + kg) * E + e) * 8) = v;
        }
    }
}

// ---------------- MFMA GRU : BM=256 x BN=32, BK=32, dbuf-A + counted vmcnt ----------------
// Staging addresses strength-reduced: per-thread bases + wave-uniform scalar ts offsets.
__global__ __launch_bounds__(256, 2) void gru_mfma(
    const unsigned short* __restrict__ u_g, const unsigned short* __restrict__ h_g,
    const unsigned short* __restrict__ wb,
    const float* __restrict__ b_ih, const float* __restrict__ b_hh,
    float* __restrict__ nxt) {

    extern __shared__ unsigned short lds[];

    int bid = blockIdx.x;
    int lbid = (bid & 7) * 2048 + (bid >> 3);   // XCD-contiguous chunks (16384 % 8 == 0)
    int eb = lbid >> 4, cb = lbid & 15;
    int e0 = eb * 256;
    int t = threadIdx.x;
    int lane = t & 63, wid = t >> 6;
    int li = lane & 15, kg = lane >> 4;
    int EB = wid * 64;

    // per-thread base pointers; per-(ts,c) deltas are wave-uniform scalars
    const unsigned short* up = u_g + (size_t)(e0 + t) * 8;
    const unsigned short* hp = h_g + (size_t)(e0 + t) * 8;
    // wb is a ushort pointer: per-cb slice is 16*6144 USHORTS; per-thread entry is t*8 ushorts.
    const unsigned short* wp = wb + (size_t)(cb * 16) * 6144 + (size_t)t * 8;   // FIXED
    int ldsb = (t & ~63) * 8;                   // wave-uniform LDS base (ushorts)

    f32x4 acc[4][4][2] = {};   // [plane][m][f]

    auto stage_a = [&](int ts, int p) {
        #pragma unroll
        for (int c = 0; c < 4; ++c)
            gl_lds16(up + (size_t)(ts * 4 + c) * (E * 8),
                     lds + p * 16384 + c * 2048 + ldsb);
        #pragma unroll
        for (int c = 0; c < 4; ++c)
            gl_lds16(hp + (size_t)(ts * 4 + c) * (E * 8),
                     lds + p * 16384 + 8192 + c * 2048 + ldsb);
    };
    auto stage_w = [&](int ts) {
        #pragma unroll
        for (int c = 0; c < 3; ++c)
            gl_lds16(wp + (size_t)(ts * 768 + c * 256) * 8,
                     lds + 32768 + c * 2048 + ldsb);
    };
    auto compute = [&](int p) {
        bf16x8 au[4], ah[4];
        #pragma unroll
        for (int m = 0; m < 4; ++m) {
            int ea = p * 16384 + (kg * 256 + EB + m * 16 + li) * 8;
            au[m] = *(bf16x8*)(lds + ea);
            ah[m] = *(bf16x8*)(lds + 8192 + ea);
        }
        const unsigned short* W = lds + 32768;
        #pragma unroll
        for (int f = 0; f < 2; ++f) {
            int cs = (f * 16 + li) ^ kg;
            bf16x8 bir = *(bf16x8*)(W + ((0 * 4 + kg) * 32 + cs) * 8);
            bf16x8 biz = *(bf16x8*)(W + ((1 * 4 + kg) * 32 + cs) * 8);
            bf16x8 bin = *(bf16x8*)(W + ((2 * 4 + kg) * 32 + cs) * 8);
            bf16x8 bhr = *(bf16x8*)(W + ((3 * 4 + kg) * 32 + cs) * 8);
            bf16x8 bhz = *(bf16x8*)(W + ((4 * 4 + kg) * 32 + cs) * 8);
            bf16x8 bhn = *(bf16x8*)(W + ((5 * 4 + kg) * 32 + cs) * 8);
            #pragma unroll
            for (int m = 0; m < 4; ++m) {
                acc[0][m][f] = __builtin_amdgcn_mfma_f32_16x16x32_bf16(au[m], bir, acc[0][m][f], 0, 0, 0);
                acc[0][m][f] = __builtin_amdgcn_mfma_f32_16x16x32_bf16(ah[m], bhr, acc[0][m][f], 0, 0, 0);
                acc[1][m][f] = __builtin_amdgcn_mfma_f32_16x16x32_bf16(au[m], biz, acc[1][m][f], 0, 0, 0);
                acc[1][m][f] = __builtin_amdgcn_mfma_f32_16x16x32_bf16(ah[m], bhz, acc[1][m][f], 0, 0, 0);
                acc[2][m][f] = __builtin_amdgcn_mfma_f32_16x16x32_bf16(au[m], bin, acc[2][m][f], 0, 0, 0);
                acc[3][m][f] = __builtin_amdgcn_mfma_f32_16x16x32_bf16(ah[m], bhn, acc[3][m][f], 0, 0, 0);
            }
        }
    };

    // prologue: tile 0 in flight (11 ops/thread)
    stage_a(0, 0);
    stage_w(0);

    for (int ts = 0; ts < 15; ++ts) {
        int p = ts & 1;
        stage_a(ts + 1, p ^ 1);                     // +8 in flight
        asm volatile("s_waitcnt vmcnt(8)" ::: "memory");
        __builtin_amdgcn_s_barrier();
        compute(p);
        asm volatile("" ::: "memory");
        __builtin_amdgcn_s_barrier();               // all waves done with W(ts) + bufA[p]
        stage_w(ts + 1);                            // +3 in flight
    }
    asm volatile("s_waitcnt vmcnt(0)" ::: "memory");
    __builtin_amdgcn_s_barrier();
    compute(1);                                     // ts = 15

    // epilogue: gates f32, hprev from h_g (bf16), fast tanh/sigmoid via __expf
    #pragma unroll
    for (int f = 0; f < 2; ++f) {
        int c = cb * 32 + f * 16 + li;
        float br = b_ih[c] + b_hh[c];
        float bz = b_ih[c + 512] + b_hh[c + 512];
        float bi = b_ih[c + 1024];
        float bh = b_hh[c + 1024];
        size_t hb = (size_t)(c >> 3) * E * 8 + (c & 7);
        #pragma unroll
        for (int m = 0; m < 4; ++m) {
            #pragma unroll
            for (int q = 0; q < 4; ++q) {
                size_t ge = (size_t)(e0 + EB + m * 16 + kg * 4 + q);
                float r = 1.f / (1.f + __expf(-(acc[0][m][f][q] + br)));
                float z = 1.f / (1.f + __expf(-(acc[1][m][f][q] + bz)));
                float xn = acc[2][m][f][q] + bi + r * (acc[3][m][f][q] + bh);
                float n = 1.f - 2.f / (__expf(2.f * xn) + 1.f);
                float hp2 = bf2f(h_g[hb + ge * 8]);
                nxt[ge * 512 + c] = (1.f - z) * n + z * hp2;
            }
        }
    }
}

// ---------------- Persistent-weight MFMA MLP (fc2 operand-swapped) ----------------
// 256 blocks x 512 threads (2 groups of 4 waves). B1+B2 staged ONCE (64 KB LDS).
// LDS ushorts: B1 [0,16384) | B2 [16384,32768) | A1 [32768 + grp*4096) | Y1 [40960 + grp*16384)
__global__ __launch_bounds__(512, 1) void mlp_fused(
    float* __restrict__ slots,
    const unsigned short* __restrict__ B1img, const unsigned short* __restrict__ B2img,
    const float* __restrict__ lnw, const float* __restrict__ lnb,
    const float* __restrict__ fc1b, const float* __restrict__ fc2b,
    unsigned short* __restrict__ h_g, int write_hg,
    const float* __restrict__ lnsw, const float* __restrict__ lnsb,
    const float* __restrict__ vb, const int* __restrict__ eidx,
    float* __restrict__ alpha_out, unsigned* __restrict__ segmax) {

    extern __shared__ unsigned short mlds[];
    unsigned short* B1 = mlds;
    unsigned short* B2 = mlds + 16384;

    int t = threadIdx.x;
    int lane = t & 63;
    int li = lane & 15, kg = lane >> 4;
    int wid = t >> 6;
    int grp = wid >> 2, wl = wid & 3;
    int tt = t & 255;                       // thread id within group
    unsigned short* A1 = mlds + 32768 + grp * 4096;
    unsigned short* Y1 = mlds + 40960 + grp * 16384;

    // ---- stage all weights once (4096 x 16B entries) ----
    #pragma unroll
    for (int c = 0; c < 8; ++c) {
        int i = c * 512 + t;
        const unsigned short* gp = (i < 2048) ? B1img + (size_t)i * 8
                                              : B2img + (size_t)(i - 2048) * 8;
        gl_lds16(gp, mlds + (size_t)(c * 512 + (t & ~63)) * 8);
    }

    int base = blockIdx.x * 128;            // 128 tiles per block
    int r = tt >> 2, c0 = (tt & 3) * 16;    // phase-0 role: row r, cols [c0,c0+16)

    // prologue: load rows of first tile
    float4 xr0, xr1, xr2, xr3;
    {
        const float* rowp = slots + ((size_t)(base + grp) * 64 + r) * 64 + c0;
        xr0 = ((const float4*)rowp)[0]; xr1 = ((const float4*)rowp)[1];
        xr2 = ((const float4*)rowp)[2]; xr3 = ((const float4*)rowp)[3];
    }
    asm volatile("s_waitcnt vmcnt(0)" ::: "memory");   // weights + first rows ready
    __syncthreads();

    for (int j = 0; j < 64; ++j) {
        int tile = base + 2 * j + grp;
        size_t p0 = (size_t)tile * 64;

        // ---- phase 0: LN from regs -> A1 frag tile ----
        {
            float s = xr0.x + xr0.y + xr0.z + xr0.w + xr1.x + xr1.y + xr1.z + xr1.w
                    + xr2.x + xr2.y + xr2.z + xr2.w + xr3.x + xr3.y + xr3.z + xr3.w;
            s += __shfl_xor(s, 1, 64); s += __shfl_xor(s, 2, 64);
            float m = s * (1.f / 64.f);
            float xv[16] = {xr0.x, xr0.y, xr0.z, xr0.w, xr1.x, xr1.y, xr1.z, xr1.w,
                            xr2.x, xr2.y, xr2.z, xr2.w, xr3.x, xr3.y, xr3.z, xr3.w};
            float sq = 0.f;
            #pragma unroll
            for (int i = 0; i < 16; ++i) { float dd = xv[i] - m; sq += dd * dd; }
            sq += __shfl_xor(sq, 1, 64); sq += __shfl_xor(sq, 2, 64);
            float rs = rsqrtf(sq * (1.f / 64.f) + 1e-5f);
            unsigned short u[16];
            #pragma unroll
            for (int i = 0; i < 16; ++i)
                u[i] = f2bf((xv[i] - m) * rs * lnw[c0 + i] + lnb[c0 + i]);
            int g0 = (tt & 3) * 2, g1 = g0 + 1;
            *(bf16x8*)(A1 + g0 * 512 + ((r * 8) ^ ((g0 & 3) * 8))) = *(bf16x8*)&u[0];
            *(bf16x8*)(A1 + g1 * 512 + ((r * 8) ^ ((g1 & 3) * 8))) = *(bf16x8*)&u[8];
        }
        // prefetch next tile's rows (latency hides under fc1+fc2)
        float4 xn0, xn1, xn2, xn3;
        if (j + 1 < 64) {
            const float* rowp = slots + ((size_t)(base + 2 * (j + 1) + grp) * 64 + r) * 64 + c0;
            xn0 = ((const float4*)rowp)[0]; xn1 = ((const float4*)rowp)[1];
            xn2 = ((const float4*)rowp)[2]; xn3 = ((const float4*)rowp)[3];
        }
        __syncthreads();                     // A1 visible; prev Y1 reads done

        // ---- fc1 (swapped operands) ----
        f32x4 acc1[4][4] = {};
        #pragma unroll
        for (int kt = 0; kt < 2; ++kt) {
            bf16x8 bfrag[4];
            #pragma unroll
            for (int rt = 0; rt < 4; ++rt)
                bfrag[rt] = *(bf16x8*)(A1 + (kt * 4 + kg) * 512 + (((rt * 16 + li) * 8) ^ (kg * 8)));
            #pragma unroll
            for (int ct = 0; ct < 4; ++ct) {
                bf16x8 af = *(bf16x8*)(B1 + kt * 8192 + kg * 2048 + (((wl * 64 + ct * 16 + li) ^ kg) * 8));
                #pragma unroll
                for (int rt = 0; rt < 4; ++rt)
                    acc1[ct][rt] = __builtin_amdgcn_mfma_f32_16x16x32_bf16(af, bfrag[rt], acc1[ct][rt], 0, 0, 0);
            }
        }
        // ---- bias + relu -> Y1 ----
        #pragma unroll
        for (int ct = 0; ct < 4; ++ct) {
            int cc = wl * 64 + ct * 16 + kg * 4;
            float4 b1 = *(const float4*)(fc1b + cc);
            int g = cc >> 3;
            #pragma unroll
            for (int rt = 0; rt < 4; ++rt) {
                f32x4 vv = acc1[ct][rt];
                float y0 = fmaxf(vv[0] + b1.x, 0.f), y1v = fmaxf(vv[1] + b1.y, 0.f);
                float y2 = fmaxf(vv[2] + b1.z, 0.f), y3 = fmaxf(vv[3] + b1.w, 0.f);
                unsigned lo = (unsigned)f2bf(y0) | ((unsigned)f2bf(y1v) << 16);
                unsigned hi = (unsigned)f2bf(y2) | ((unsigned)f2bf(y3) << 16);
                int rr = rt * 16 + li;
                int off = g * 512 + ((rr * 8) ^ ((g & 3) * 8)) + (cc & 7);
                uint2 pk; pk.x = lo; pk.y = hi;
                *(uint2*)(Y1 + off) = pk;
            }
        }
        __syncthreads();                     // Y1 visible

        // ---- fc2 SWAPPED: acc2[ct] = mfma(W2frag, Y1frag) ----
        // lane (li,kg) ends owning row rr = wl*16+li, cols ct*16+kg*4+(0..3)
        f32x4 acc2[4] = {};
        #pragma unroll
        for (int hc = 0; hc < 2; ++hc) {
            #pragma unroll
            for (int ktl = 0; ktl < 4; ++ktl) {
                int ktg = hc * 4 + ktl;
                bf16x8 yf = *(bf16x8*)(Y1 + (ktg * 4 + kg) * 512 + (((wl * 16 + li) * 8) ^ (kg * 8)));
                #pragma unroll
                for (int ct = 0; ct < 4; ++ct) {
                    bf16x8 wf = *(bf16x8*)(B2 + ktg * 2048 + kg * 512 + (((ct * 16 + li) ^ kg) * 8));
                    acc2[ct] = __builtin_amdgcn_mfma_f32_16x16x32_bf16(wf, yf, acc2[ct], 0, 0, 0);
                }
            }
        }

        // ---- epilogue: vectorized residual add (1 row x 4 float4 per thread) ----
        int rr = wl * 16 + li;
        float* rowp = slots + (p0 + rr) * 64;
        float vals[4][4];
        #pragma unroll
        for (int ct = 0; ct < 4; ++ct) {
            int dd0 = ct * 16 + kg * 4;
            float4 b2 = *(const float4*)(fc2b + dd0);
            float4 sv = *(const float4*)(rowp + dd0);
            vals[ct][0] = sv.x + acc2[ct][0] + b2.x;
            vals[ct][1] = sv.y + acc2[ct][1] + b2.y;
            vals[ct][2] = sv.z + acc2[ct][2] + b2.z;
            vals[ct][3] = sv.w + acc2[ct][3] + b2.w;
            float4 ov; ov.x = vals[ct][0]; ov.y = vals[ct][1];
            ov.z = vals[ct][2]; ov.w = vals[ct][3];
            *(float4*)(rowp + dd0) = ov;
            uint2 pk;
            pk.x = (unsigned)f2bf(vals[ct][0]) | ((unsigned)f2bf(vals[ct][1]) << 16);
            pk.y = (unsigned)f2bf(vals[ct][2]) | ((unsigned)f2bf(vals[ct][3]) << 16);
            *(uint2*)(A1 + rr * 64 + dd0) = pk;
        }
        if (write_hg) {
            // ---- fused alpha: row rr owned by 4 lanes (kg); butterfly over kg ----
            float s = 0.f;
            #pragma unroll
            for (int ct = 0; ct < 4; ++ct)
                s += vals[ct][0] + vals[ct][1] + vals[ct][2] + vals[ct][3];
            s += __shfl_xor(s, 16, 64); s += __shfl_xor(s, 32, 64);
            float mean = s * (1.f / 64.f);
            float sq = 0.f;
            #pragma unroll
            for (int ct = 0; ct < 4; ++ct)
                #pragma unroll
                for (int q = 0; q < 4; ++q) { float d = vals[ct][q] - mean; sq += d * d; }
            sq += __shfl_xor(sq, 16, 64); sq += __shfl_xor(sq, 32, 64);
            float rs = rsqrtf(sq * (1.f / 64.f) + 1e-5f);
            int h = rr & 7;
            float dp = 0.f;
            #pragma unroll
            for (int ct = 0; ct < 4; ++ct) {
                int dd0 = ct * 16 + kg * 4;
                float4 lw = *(const float4*)(lnsw + dd0);
                float4 lb = *(const float4*)(lnsb + dd0);
                float4 vv = *(const float4*)(vb + h * 64 + dd0);
                dp += ((vals[ct][0] - mean) * rs * lw.x + lb.x) * vv.x
                    + ((vals[ct][1] - mean) * rs * lw.y + lb.y) * vv.y
                    + ((vals[ct][2] - mean) * rs * lw.z + lb.z) * vv.z
                    + ((vals[ct][3] - mean) * rs * lw.w + lb.w) * vv.w;
            }
            dp += __shfl_xor(dp, 16, 64); dp += __shfl_xor(dp, 32, 64);
            if (kg == 0) {
                float a = dp * 0.125f;
                a = a >= 0.f ? a : 0.2f * a;
                size_t p = p0 + rr;
                alpha_out[p] = a;
                int e = (int)(p >> 3);
                unsigned b = __float_as_uint(a);
                unsigned enc = (b & 0x80000000u) ? ~b : (b | 0x80000000u);
                atomicMax(&segmax[eidx[e] * 8 + h], enc);
            }
            __syncthreads();                 // A1 stash visible within group
            #pragma unroll
            for (int c2 = 0; c2 < 2; ++c2) {
                int n = c2 * 256 + tt;       // (h*8+g)*8 + eloc
                int eloc = n & 7;
                int hg8 = n >> 3;
                int hh = hg8 >> 3, g = hg8 & 7;
                int r2 = eloc * 8 + hh;
                bf16x8 v = *(bf16x8*)(A1 + r2 * 64 + g * 8);
                int k = hh * 64 + g * 8;
                int ts = k >> 5, kgg = (k >> 3) & 3;
                size_t e = (size_t)tile * 8 + eloc;
                *(bf16x8*)(h_g + ((size_t)(ts * 4 + kgg) * E + e) * 8) = v;
            }
        }
        __syncthreads();                     // A1/Y1 free for next iteration
        xr0 = xn0; xr1 = xn1; xr2 = xn2; xr3 = xn3;
    }
}

extern "C" void kernel_launch(void* const* d_in, const int* in_sizes, int n_in,
                              void* d_out, int out_size, void* d_ws, size_t ws_size,
                              hipStream_t stream) {
    const float* x     = (const float*)d_in[0];
    const int*   eidx  = (const int*)d_in[1];
    const float* nd    = (const float*)d_in[3];
    const float* mu    = (const float*)d_in[4];
    const float* lsig  = (const float*)d_in[5];
    const float* atten = (const float*)d_in[6];
    const float* ln_sw = (const float*)d_in[7];
    const float* ln_sb = (const float*)d_in[8];
    const float* ln_mw = (const float*)d_in[9];
    const float* ln_mb = (const float*)d_in[10];
    const float* Wq    = (const float*)d_in[11];
    const float* Wk    = (const float*)d_in[12];
    const float* w_ih  = (const float*)d_in[13];
    const float* w_hh  = (const float*)d_in[14];
    const float* b_ih  = (const float*)d_in[15];
    const float* b_hh  = (const float*)d_in[16];
    const float* fc1w  = (const float*)d_in[17];
    const float* fc1b  = (const float*)d_in[18];
    const float* fc2w  = (const float*)d_in[19];
    const float* fc2b  = (const float*)d_in[20];

    float* out = (float*)d_out;
    char* ws = (char*)d_ws;
    size_t off = 0;
    auto alloc = [&](size_t nbytes) {
        void* p = ws + off;
        off += (nbytes + 255) & ~(size_t)255;
        return p;
    };
    float*          slotsA = (float*)alloc((size_t)E * HD * 4);
    float*          kbuf   = (float*)alloc((size_t)E * 64 * 4);
    float*          alpha  = (float*)alloc((size_t)E * 8 * 4);
    unsigned*       segmax = (unsigned*)alloc((size_t)Nn * 8 * 4);
    float*          segsum = (float*)alloc((size_t)Nn * 8 * 4);
    float*          vbuf   = (float*)alloc(512 * 4);
    unsigned short* B1img  = (unsigned short*)alloc(16384 * 2);
    unsigned short* B2img  = (unsigned short*)alloc(16384 * 2);
    unsigned short* wb     = (unsigned short*)alloc((size_t)1572864 * 2);
    unsigned short* u_g    = (unsigned short*)alloc((size_t)E * HD * 2);
    unsigned short* h_g    = (unsigned short*)alloc((size_t)E * HD * 2);

    const int GRU_LDS_BYTES = 4864 * 16;    // 76 KB
    const int MLP_LDS_BYTES = 73728 * 2;    // 144 KB
    hipFuncSetAttribute((const void*)gru_mfma,
                        hipFuncAttributeMaxDynamicSharedMemorySize, GRU_LDS_BYTES);
    hipFuncSetAttribute((const void*)mlp_fused,
                        hipFuncAttributeMaxDynamicSharedMemorySize, MLP_LDS_BYTES);

    prep_v<<<1, 512, 0, stream>>>(atten, Wq, vbuf);
    prep_mlp<<<128, 256, 0, stream>>>(fc1w, fc2w, B1img, B2img);
    wprep<<<6144, 256, 0, stream>>>(w_ih, w_hh, wb);
    compute_k<<<4096, 256, 0, stream>>>(x, Wk, kbuf);
    seg_init<<<512, 256, 0, stream>>>(segmax, segsum);
    init_slots<<<2048, 256, 0, stream>>>(nd, mu, lsig, slotsA, h_g,
                                         ln_sw, ln_sb, vbuf, eidx, alpha, segmax);

    float* cur = slotsA;
    float* nxt = out;
    for (int it = 0; it < 3; ++it) {
        exp_sum<<<E * 8 / 256, 256, 0, stream>>>(eidx, segmax, alpha, segsum);
        prep_u<<<E / 256, 256, 0, stream>>>(kbuf, alpha, segsum, eidx, u_g);
        gru_mfma<<<16384, 256, GRU_LDS_BYTES, stream>>>(u_g, h_g, wb, b_ih, b_hh, nxt);
        if (it < 2)
            seg_init<<<512, 256, 0, stream>>>(segmax, segsum);
        mlp_fused<<<256, 512, MLP_LDS_BYTES, stream>>>(nxt, B1img, B2img, ln_mw, ln_mb,
                                                       fc1b, fc2b, h_g, (it < 2) ? 1 : 0,
                                                       ln_sw, ln_sb, vbuf, eidx, alpha, segmax);
        float* tmp = cur; cur = nxt; nxt = tmp;
    }
    (void)in_sizes; (void)n_in; (void)out_size; (void)ws_size;
}